// Round 7
// baseline (422.618 us; speedup 1.0000x reference)
//
#include <hip/hip_runtime.h>
#include <cstdint>

#define NN 100000
#define NE 1600000
#define NG 64
#define NH 128
#define NC 10
#define EPSV 1e-5f

#define NB 782                       // (NN+127)>>7 coarse buckets (128 nodes each)
#define NBLK 512                     // histogram/scatter blocks
#define EPB ((NE + NBLK - 1) / NBLK) // 3125 edges per block
#define NSCAN (NB * NBLK)            // 400384, divisible by 1024
#define NSB (NSCAN / 1024)           // 391 scan blocks
#define PS ((size_t)NN * 16)         // plane stride in ushorts (16 feats/plane, 8 planes)
#define NCH ((NN + 63) / 64)         // 1563 node chunks for k_agg

typedef __attribute__((ext_vector_type(8))) short bf16x8;
typedef __attribute__((ext_vector_type(4))) float f32x4;
typedef unsigned long long u64;

__device__ __forceinline__ ushort f2b(float f) {
  uint u = __builtin_bit_cast(uint, f);
  u = (u + 0x7FFFu + ((u >> 16) & 1u)) >> 16;
  return (ushort)u;
}
__device__ __forceinline__ float b2f(ushort h) {
  return __builtin_bit_cast(float, ((uint)h) << 16);
}
__device__ __forceinline__ float lo2f(uint v) { return __builtin_bit_cast(float, v << 16); }
__device__ __forceinline__ float hi2f(uint v) { return __builtin_bit_cast(float, v & 0xFFFF0000u); }

// ---------------- graph prep: counting sort by destination ----------------

__global__ __launch_bounds__(128) void k_gstart2(const int* __restrict__ batch,
                                                 int* __restrict__ gstart, int* __restrict__ counts) {
  __shared__ int lb[NG + 1];
  int t = threadIdx.x;
  if (t <= NG) {                      // first index with batch[i] >= t (batch is sorted)
    int lo = 0, hi = NN;
    while (lo < hi) { int mid = (lo + hi) >> 1; if (batch[mid] < t) lo = mid + 1; else hi = mid; }
    lb[t] = lo;
  }
  __syncthreads();
  if (t < NG) { gstart[t] = lb[t]; counts[t] = lb[t + 1] - lb[t]; }
  if (t == 0) gstart[NG] = NN;
}

__global__ __launch_bounds__(256) void k_hist(const int* __restrict__ ei, int* __restrict__ ghist) {
  __shared__ int h[NB];
  int t = threadIdx.x, blk = blockIdx.x;
  for (int i = t; i < NB; i += 256) h[i] = 0;
  __syncthreads();
  int e0 = blk * EPB, e1 = min(NE, e0 + EPB);
  for (int e = e0 + t; e < e1; e += 256) atomicAdd(&h[ei[NE + e] >> 7], 1);
  __syncthreads();
  for (int i = t; i < NB; i += 256) ghist[i * NBLK + blk] = h[i];
}

__global__ __launch_bounds__(256) void k_scan1g(int* __restrict__ data, int* __restrict__ bsums) {
  __shared__ int sh[256];
  int t = threadIdx.x;
  int base = blockIdx.x * 1024 + t * 4;
  int4 v = *reinterpret_cast<const int4*>(data + base);
  int s = v.x + v.y + v.z + v.w;
  sh[t] = s;
  __syncthreads();
  for (int o = 1; o < 256; o <<= 1) {
    int x = (t >= o) ? sh[t - o] : 0;
    __syncthreads();
    sh[t] += x;
    __syncthreads();
  }
  int ex = sh[t] - s;
  int4 o4;
  o4.x = ex; o4.y = ex + v.x; o4.z = ex + v.x + v.y; o4.w = ex + v.x + v.y + v.z;
  *reinterpret_cast<int4*>(data + base) = o4;
  if (t == 255) bsums[blockIdx.x] = sh[255];
}

__global__ __launch_bounds__(512) void k_scan2(int* bsums, int nb) {
  __shared__ int sh[512];
  int t = threadIdx.x;
  int v = (t < nb) ? bsums[t] : 0;
  sh[t] = v;
  __syncthreads();
  for (int o = 1; o < 512; o <<= 1) {
    int x = (t >= o) ? sh[t - o] : 0;
    __syncthreads();
    sh[t] += x;
    __syncthreads();
  }
  if (t < nb) bsums[t] = sh[t] - v;   // exclusive
}

__global__ __launch_bounds__(256) void k_scan3g(int* __restrict__ data, const int* __restrict__ bsums) {
  int t = threadIdx.x;
  int base = blockIdx.x * 1024 + t * 4;
  int add = bsums[blockIdx.x];
  int4 v = *reinterpret_cast<int4*>(data + base);
  v.x += add; v.y += add; v.z += add; v.w += add;
  *reinterpret_cast<int4*>(data + base) = v;
}

__global__ __launch_bounds__(256) void k_scatter(const int* __restrict__ ei, const int* __restrict__ ghist,
                                                 int2* __restrict__ tmp) {
  __shared__ int cur[NB];
  int t = threadIdx.x, blk = blockIdx.x;
  for (int i = t; i < NB; i += 256) cur[i] = ghist[i * NBLK + blk];
  __syncthreads();
  int e0 = blk * EPB, e1 = min(NE, e0 + EPB);
  for (int e = e0 + t; e < e1; e += 256) {
    int d = ei[NE + e], s = ei[e];
    int p = atomicAdd(&cur[d >> 7], 1);   // LDS atomic (fast, block-local)
    tmp[p] = make_int2(d, s);
  }
}

// fine bucket: per-node deg/offs/dis + CSR (unsorted rows — fast version)
__global__ __launch_bounds__(256) void k_fine(const int2* __restrict__ tmp, const int* __restrict__ ghist,
                                              int* __restrict__ deg, int* __restrict__ offs,
                                              float* __restrict__ dis, int* __restrict__ csr) {
  __shared__ int fh[128], fsc[128], fc[128];
  int b = blockIdx.x, t = threadIdx.x;
  int bs = ghist[b * NBLK];
  int be = (b + 1 < NB) ? ghist[(b + 1) * NBLK] : NE;
  if (t < 128) fh[t] = 0;
  __syncthreads();
  for (int e = bs + t; e < be; e += 256) atomicAdd(&fh[tmp[e].x & 127], 1);
  __syncthreads();
  if (t < 128) fsc[t] = fh[t];
  __syncthreads();
  for (int o = 1; o < 128; o <<= 1) {
    int x = 0;
    if (t < 128 && t >= o) x = fsc[t - o];
    __syncthreads();
    if (t < 128) fsc[t] += x;
    __syncthreads();
  }
  if (t < 128) {
    int ex = fsc[t] - fh[t];
    int node = b * 128 + t;
    fc[t] = bs + ex;
    if (node < NN) {
      deg[node] = fh[t];
      offs[node] = bs + ex;
      dis[node] = rsqrtf((float)(fh[t] + 1));   // +1 self-loop
    }
  }
  __syncthreads();
  for (int e = bs + t; e < be; e += 256) {
    int2 ds = tmp[e];
    int p = atomicAdd(&fc[ds.x & 127], 1);
    csr[p] = ds.y;
  }
}

// ---------------- W pre-pack: fragment-major bf16 B-operand (both layers) ----------------
__global__ __launch_bounds__(256) void k_prepw(const float* __restrict__ W1, ushort* __restrict__ WF1,
                                               const float* __restrict__ W2, ushort* __restrict__ WF2) {
  int tt = blockIdx.x * 256 + threadIdx.x;
  if (tt >= 4096) return;
  const float* W = (tt < 2048) ? W1 : W2;
  ushort* WF = (tt < 2048) ? WF1 : WF2;
  int t = tt & 2047;
  int lane = t & 63, nk = t >> 6;
  int n = nk >> 2, ks = nk & 3;
  int col = n * 16 + (lane & 15);
  int k0 = ks * 32 + (lane >> 4) * 8;
#pragma unroll
  for (int j = 0; j < 8; ++j) WF[(size_t)t * 8 + j] = f2b(W[(k0 + j) * NH + col]);
}

// ---------------- MFMA GEMM: hs = (norm?(X) @ W) * dis  (bf16 out, 8-plane-16 layout) ----------------
// Wave = 16 rows x 128 cols. Block = 4 waves = 64 rows. No LDS.
template <bool NORM>
__global__ __launch_bounds__(256) void k_gemm(const void* __restrict__ Xv, const ushort* __restrict__ WF,
                                              const float* __restrict__ dis, const int* __restrict__ batch,
                                              const float* __restrict__ Aaff, const float* __restrict__ Baff,
                                              ushort* __restrict__ out) {
  int t = threadIdx.x;
  int w = t >> 6, lane = t & 63;
  int r0 = blockIdx.x * 64 + w * 16;
  int arow = r0 + (lane & 15);
  int khi = lane >> 4;                    // 0..3
  int arowc = (arow < NN) ? arow : (NN - 1);

  f32x4 acc[8];
#pragma unroll
  for (int n = 0; n < 8; ++n) acc[n] = (f32x4){0.f, 0.f, 0.f, 0.f};

  int g = 0;
  if (NORM) g = batch[arowc];
  const bf16x8* WFv = reinterpret_cast<const bf16x8*>(WF);

#pragma unroll
  for (int ks = 0; ks < 4; ++ks) {
    int k0 = ks * 32 + khi * 8;
    bf16x8 a;
    if (!NORM) {
      const float* X = (const float*)Xv;
      float4 x0 = *reinterpret_cast<const float4*>(X + (size_t)arowc * NH + k0);
      float4 x1 = *reinterpret_cast<const float4*>(X + (size_t)arowc * NH + k0 + 4);
      a[0] = (short)f2b(x0.x); a[1] = (short)f2b(x0.y); a[2] = (short)f2b(x0.z); a[3] = (short)f2b(x0.w);
      a[4] = (short)f2b(x1.x); a[5] = (short)f2b(x1.y); a[6] = (short)f2b(x1.z); a[7] = (short)f2b(x1.w);
    } else {
      const ushort* X = (const ushort*)Xv;   // 8-plane-16 bf16 layout
      int plane = k0 >> 4;
      const ushort* Xp = X + (size_t)plane * PS + (size_t)arowc * 16 + (k0 & 15);
      bf16x8 xr = *reinterpret_cast<const bf16x8*>(Xp);
      float4 A0 = *reinterpret_cast<const float4*>(Aaff + g * NH + k0);
      float4 A1 = *reinterpret_cast<const float4*>(Aaff + g * NH + k0 + 4);
      float4 B0 = *reinterpret_cast<const float4*>(Baff + g * NH + k0);
      float4 B1 = *reinterpret_cast<const float4*>(Baff + g * NH + k0 + 4);
      a[0] = (short)f2b(fmaf(A0.x, b2f((ushort)xr[0]), B0.x));
      a[1] = (short)f2b(fmaf(A0.y, b2f((ushort)xr[1]), B0.y));
      a[2] = (short)f2b(fmaf(A0.z, b2f((ushort)xr[2]), B0.z));
      a[3] = (short)f2b(fmaf(A0.w, b2f((ushort)xr[3]), B0.w));
      a[4] = (short)f2b(fmaf(A1.x, b2f((ushort)xr[4]), B1.x));
      a[5] = (short)f2b(fmaf(A1.y, b2f((ushort)xr[5]), B1.y));
      a[6] = (short)f2b(fmaf(A1.z, b2f((ushort)xr[6]), B1.z));
      a[7] = (short)f2b(fmaf(A1.w, b2f((ushort)xr[7]), B1.w));
    }
#pragma unroll
    for (int n = 0; n < 8; ++n) {
      bf16x8 b = WFv[(n * 4 + ks) * 64 + lane];
      acc[n] = __builtin_amdgcn_mfma_f32_16x16x32_bf16(a, b, acc[n], 0, 0, 0);
    }
  }

  // D: col = n*16 + (lane&15) -> plane n, offset colb; row = r0 + khi*4 + reg
  int colb = lane & 15;
#pragma unroll
  for (int reg = 0; reg < 4; ++reg) {
    int row = r0 + khi * 4 + reg;
    if (row < NN) {
      float d = dis[row];
#pragma unroll
      for (int n = 0; n < 8; ++n)
        out[(size_t)n * PS + (size_t)row * 16 + colb] = f2b(acc[n][reg] * d);
    }
  }
}

// ---------------- aggregation: one plane (16 feats) per XCD via blockIdx&7 ----------------
// t = relu(dis[i]*(hs[i]+sum_src hs[src]) + b). 4 lanes per node (8B = 4 feats each).
__global__ __launch_bounds__(256) void k_agg(const ushort* __restrict__ hs, const int* __restrict__ offs,
                                             const int* __restrict__ deg, const int* __restrict__ csr,
                                             const float* __restrict__ dis, const float* __restrict__ bias,
                                             ushort* __restrict__ out) {
  int p = blockIdx.x & 7;               // plane -> XCD (round-robin block dispatch)
  int chunk = blockIdx.x >> 3;
  int t = threadIdx.x;
  int node = chunk * 64 + (t >> 2);
  if (node >= NN) return;
  int u2 = t & 3;
  const u64* hp = reinterpret_cast<const u64*>(hs) + (size_t)p * NN * 4;
  u64 self = hp[(size_t)node * 4 + u2];
  uint sx = (uint)self, sy = (uint)(self >> 32);
  float a0 = lo2f(sx), a1 = hi2f(sx), a2 = lo2f(sy), a3 = hi2f(sy);
  int beg = __builtin_nontemporal_load(offs + node);
  int cnt = __builtin_nontemporal_load(deg + node);
  int i = 0;
  for (; i + 8 <= cnt; i += 8) {
    int s0 = __builtin_nontemporal_load(csr + beg + i + 0);
    int s1 = __builtin_nontemporal_load(csr + beg + i + 1);
    int s2 = __builtin_nontemporal_load(csr + beg + i + 2);
    int s3 = __builtin_nontemporal_load(csr + beg + i + 3);
    int s4 = __builtin_nontemporal_load(csr + beg + i + 4);
    int s5 = __builtin_nontemporal_load(csr + beg + i + 5);
    int s6 = __builtin_nontemporal_load(csr + beg + i + 6);
    int s7 = __builtin_nontemporal_load(csr + beg + i + 7);
    u64 v0 = hp[(size_t)s0 * 4 + u2];
    u64 v1 = hp[(size_t)s1 * 4 + u2];
    u64 v2 = hp[(size_t)s2 * 4 + u2];
    u64 v3 = hp[(size_t)s3 * 4 + u2];
    u64 v4 = hp[(size_t)s4 * 4 + u2];
    u64 v5 = hp[(size_t)s5 * 4 + u2];
    u64 v6 = hp[(size_t)s6 * 4 + u2];
    u64 v7 = hp[(size_t)s7 * 4 + u2];
    uint w0 = (uint)v0, w1 = (uint)v1, w2 = (uint)v2, w3 = (uint)v3;
    uint w4 = (uint)v4, w5 = (uint)v5, w6 = (uint)v6, w7 = (uint)v7;
    uint h0 = (uint)(v0 >> 32), h1 = (uint)(v1 >> 32), h2 = (uint)(v2 >> 32), h3 = (uint)(v3 >> 32);
    uint h4 = (uint)(v4 >> 32), h5 = (uint)(v5 >> 32), h6 = (uint)(v6 >> 32), h7 = (uint)(v7 >> 32);
    a0 += lo2f(w0) + lo2f(w1) + lo2f(w2) + lo2f(w3) + lo2f(w4) + lo2f(w5) + lo2f(w6) + lo2f(w7);
    a1 += hi2f(w0) + hi2f(w1) + hi2f(w2) + hi2f(w3) + hi2f(w4) + hi2f(w5) + hi2f(w6) + hi2f(w7);
    a2 += lo2f(h0) + lo2f(h1) + lo2f(h2) + lo2f(h3) + lo2f(h4) + lo2f(h5) + lo2f(h6) + lo2f(h7);
    a3 += hi2f(h0) + hi2f(h1) + hi2f(h2) + hi2f(h3) + hi2f(h4) + hi2f(h5) + hi2f(h6) + hi2f(h7);
  }
  for (; i < cnt; ++i) {
    int s = __builtin_nontemporal_load(csr + beg + i);
    u64 v = hp[(size_t)s * 4 + u2];
    uint wl = (uint)v, wh = (uint)(v >> 32);
    a0 += lo2f(wl); a1 += hi2f(wl); a2 += lo2f(wh); a3 += hi2f(wh);
  }
  float d = dis[node];
  const float4 b4 = *reinterpret_cast<const float4*>(bias + p * 16 + u2 * 4);
  float o0 = fmaxf(fmaf(d, a0, b4.x), 0.f);
  float o1 = fmaxf(fmaf(d, a1, b4.y), 0.f);
  float o2 = fmaxf(fmaf(d, a2, b4.z), 0.f);
  float o3 = fmaxf(fmaf(d, a3, b4.w), 0.f);
  u64 ov = (u64)((uint)f2b(o0) | ((uint)f2b(o1) << 16)) |
           ((u64)((uint)f2b(o2) | ((uint)f2b(o3) << 16)) << 32);
  u64* op = reinterpret_cast<u64*>(out) + (size_t)p * NN * 4 + (size_t)node * 4 + u2;
  __builtin_nontemporal_store(ov, op);
}

// ---------------- GraphNorm stats: per-(g,f) sum & sumsq partials (no atomics) ----------------
__global__ __launch_bounds__(256) void k_stats(const uint* __restrict__ t2, const int* __restrict__ gstart,
                                               float* __restrict__ acc) {
  int g = blockIdx.x >> 4, s = blockIdx.x & 15;
  int beg = gstart[g], end = gstart[g + 1];
  int j = threadIdx.x & 63, q = threadIdx.x >> 6;   // 4 row-groups
  int plane = j >> 3, w = j & 7;
  const uint* base = t2 + (size_t)plane * NN * 8;
  float sx = 0.f, qx = 0.f, sy = 0.f, qy = 0.f;
  for (int n = beg + s * 4 + q; n < end; n += 64) {
    uint v = base[(size_t)n * 8 + w];
    float a = lo2f(v), b = hi2f(v);
    sx += a; qx = fmaf(a, a, qx);
    sy += b; qy = fmaf(b, b, qy);
  }
  __shared__ float sh[4][256];
  sh[0][threadIdx.x] = sx; sh[1][threadIdx.x] = qx;
  sh[2][threadIdx.x] = sy; sh[3][threadIdx.x] = qy;
  __syncthreads();
  if (q == 0) {
#pragma unroll
    for (int qq = 1; qq < 4; ++qq) {
      int idx = (qq << 6) | j;
      sx += sh[0][idx]; qx += sh[1][idx];
      sy += sh[2][idx]; qy += sh[3][idx];
    }
    int f = plane * 16 + w * 2;
    float* dst = acc + (size_t)(s * NG + g) * 2 * NH;
    dst[f] = sx; dst[f + 1] = sy;
    dst[NH + f] = qx; dst[NH + f + 1] = qy;
  }
}

__global__ __launch_bounds__(128) void k_fin1(const float* __restrict__ acc, const int* __restrict__ counts,
                                              const float* __restrict__ gw, const float* __restrict__ gb,
                                              const float* __restrict__ ga,
                                              float* __restrict__ Aaff, float* __restrict__ Baff) {
  int g = blockIdx.x, f = threadIdx.x;
  float sum = 0.f, sq = 0.f;
#pragma unroll 4
  for (int s = 0; s < 16; ++s) {
    const float* d = acc + (size_t)(s * NG + g) * 2 * NH;
    sum += d[f];
    sq += d[NH + f];
  }
  float cnt = fmaxf((float)counts[g], 1.f);
  float m = sum / cnt;
  float ex2 = sq / cnt;
  float a = ga[f];
  float var = ex2 - 2.f * a * m * m + a * a * m * m;
  float rstd = rsqrtf(var + EPSV);
  float A = gw[f] * rstd;
  Aaff[g * NH + f] = A;
  Baff[g * NH + f] = gb[f] - A * a * m;
}

// fused layer-2 finalize + classifier head + softmax
__global__ __launch_bounds__(128) void k_fin2head(const float* __restrict__ acc, const int* __restrict__ counts,
                                                  const float* __restrict__ gw, const float* __restrict__ gb,
                                                  const float* __restrict__ ga, const float* __restrict__ Wc,
                                                  const float* __restrict__ bc, float* __restrict__ outp) {
  __shared__ float pool[NH];
  __shared__ float lg[NC];
  int g = blockIdx.x, f = threadIdx.x;
  float sum = 0.f, sq = 0.f;
#pragma unroll 4
  for (int s = 0; s < 16; ++s) {
    const float* d = acc + (size_t)(s * NG + g) * 2 * NH;
    sum += d[f];
    sq += d[NH + f];
  }
  float cnt = fmaxf((float)counts[g], 1.f);
  float m = sum / cnt;
  float ex2 = sq / cnt;
  float a = ga[f];
  float var = ex2 - 2.f * a * m * m + a * a * m * m;
  float rstd = rsqrtf(var + EPSV);
  pool[f] = gw[f] * rstd * (m - a * m) + gb[f];
  __syncthreads();
  if (f < NC) {
    float s = bc[f];
    for (int h = 0; h < NH; ++h) s = fmaf(pool[h], Wc[h * NC + f], s);
    lg[f] = s;
  }
  __syncthreads();
  if (f == 0) {
    float mx = lg[0];
    for (int c = 1; c < NC; ++c) mx = fmaxf(mx, lg[c]);
    float ex[NC];
    float ssum = 0.f;
    for (int c = 0; c < NC; ++c) { ex[c] = __expf(lg[c] - mx); ssum += ex[c]; }
    float inv = 1.f / ssum;
    for (int c = 0; c < NC; ++c) outp[g * NC + c] = ex[c] * inv;
  }
}

// ---------------- launch ----------------
extern "C" void kernel_launch(void* const* d_in, const int* in_sizes, int n_in,
                              void* d_out, int out_size, void* d_ws, size_t ws_size,
                              hipStream_t stream) {
  const float* x   = (const float*)d_in[0];
  const int*   ei  = (const int*)d_in[1];
  const int*   bat = (const int*)d_in[2];
  const float* W1  = (const float*)d_in[3];
  const float* b1  = (const float*)d_in[4];
  const float* gw1 = (const float*)d_in[5];
  const float* gb1 = (const float*)d_in[6];
  const float* ga1 = (const float*)d_in[7];
  const float* W2  = (const float*)d_in[8];
  const float* b2  = (const float*)d_in[9];
  const float* gw2 = (const float*)d_in[10];
  const float* gb2 = (const float*)d_in[11];
  const float* ga2 = (const float*)d_in[12];
  const float* Wc  = (const float*)d_in[13];
  const float* bc  = (const float*)d_in[14];
  float* outp = (float*)d_out;

  char* ws = (char*)d_ws;
  size_t off = 0;
  auto alloc = [&](size_t b) { size_t p = off; off += (b + 255) & ~(size_t)255; return p; };
  int*    deg     = (int*)(ws + alloc((size_t)NN * 4));
  float*  dis     = (float*)(ws + alloc((size_t)NN * 4));
  int*    counts  = (int*)(ws + alloc(NG * 4));
  int*    gstart  = (int*)(ws + alloc((NG + 1) * 4));
  int*    offs    = (int*)(ws + alloc((size_t)NN * 4));
  int*    bsums   = (int*)(ws + alloc(512 * 4));
  int*    csr     = (int*)(ws + alloc((size_t)NE * 4));
  float*  statacc = (float*)(ws + alloc((size_t)16 * NG * 2 * NH * 4));   // 1 MB partials
  float*  Aaff    = (float*)(ws + alloc((size_t)NG * NH * 4));
  float*  Baff    = (float*)(ws + alloc((size_t)NG * NH * 4));
  ushort* WF1     = (ushort*)(ws + alloc((size_t)2048 * 8 * 2));
  ushort* WF2     = (ushort*)(ws + alloc((size_t)2048 * 8 * 2));
  ushort* bufA    = (ushort*)(ws + alloc((size_t)NN * NH * 2));   // 8 planes of NN x 16
  ushort* bufB    = (ushort*)(ws + alloc((size_t)NN * NH * 2));
  // sort temps alias bufA (dead before first k_gemm writes bufA): 12.8+1.6 MB <= 25.6 MB
  int2* tmp   = (int2*)bufA;
  int*  ghist = (int*)((char*)bufA + (((size_t)NE * 8 + 255) & ~(size_t)255));
  (void)ws_size; (void)in_sizes; (void)n_in; (void)out_size;

  // prep: counts/gstart via binary search (batch sorted); CSR via counting sort
  k_gstart2<<<1, 128, 0, stream>>>(bat, gstart, counts);
  k_hist<<<NBLK, 256, 0, stream>>>(ei, ghist);
  k_scan1g<<<NSB, 256, 0, stream>>>(ghist, bsums);
  k_scan2<<<1, 512, 0, stream>>>(bsums, NSB);
  k_scan3g<<<NSB, 256, 0, stream>>>(ghist, bsums);
  k_scatter<<<NBLK, 256, 0, stream>>>(ei, ghist, tmp);
  k_fine<<<NB, 256, 0, stream>>>(tmp, ghist, deg, offs, dis, csr);
  k_prepw<<<16, 256, 0, stream>>>(W1, WF1, W2, WF2);

  int gemm_grid = (NN + 63) / 64;   // 1563
  int agg_grid  = NCH * 8;          // 12504: plane = bid&7 -> XCD affinity

  // layer 1
  k_gemm<false><<<gemm_grid, 256, 0, stream>>>(x, WF1, dis, bat, nullptr, nullptr, bufA);
  k_agg<<<agg_grid, 256, 0, stream>>>(bufA, offs, deg, csr, dis, b1, bufB);
  k_stats<<<NG * 16, 256, 0, stream>>>((const uint*)bufB, gstart, statacc);
  k_fin1<<<NG, 128, 0, stream>>>(statacc, counts, gw1, gb1, ga1, Aaff, Baff);

  // layer 2 (norm fused into GEMM A-fragment load)
  k_gemm<true><<<gemm_grid, 256, 0, stream>>>(bufB, WF2, dis, bat, Aaff, Baff, bufA);
  k_agg<<<agg_grid, 256, 0, stream>>>(bufA, offs, deg, csr, dis, b2, bufB);
  k_stats<<<NG * 16, 256, 0, stream>>>((const uint*)bufB, gstart, statacc);
  k_fin2head<<<NG, 128, 0, stream>>>(statacc, counts, gw2, gb2, ga2, Wc, bc, outp);
}

// Round 8
// 310.031 us; speedup vs baseline: 1.3631x; 1.3631x over previous
//
#include <hip/hip_runtime.h>
#include <cstdint>

#define NN 100000
#define NE 1600000
#define NG 64
#define NH 128
#define NC 10
#define EPSV 1e-5f

#define NB 782                       // (NN+127)>>7 coarse buckets (128 nodes each)
#define NBLK 512                     // histogram/scatter blocks
#define EPB ((NE + NBLK - 1) / NBLK) // 3125 edges per block
#define NSCAN (NB * NBLK)            // 400384, divisible by 1024
#define NSB (NSCAN / 1024)           // 391 scan blocks

typedef __attribute__((ext_vector_type(8))) short bf16x8;
typedef __attribute__((ext_vector_type(4))) float f32x4;
typedef __attribute__((ext_vector_type(2))) float f32x2;
typedef unsigned long long u64;
typedef unsigned char uchar;

__device__ __forceinline__ ushort f2b(float f) {
  uint u = __builtin_bit_cast(uint, f);
  u = (u + 0x7FFFu + ((u >> 16) & 1u)) >> 16;
  return (ushort)u;
}
__device__ __forceinline__ float b2f(ushort h) {
  return __builtin_bit_cast(float, ((uint)h) << 16);
}
__device__ __forceinline__ float lo2f(uint v) { return __builtin_bit_cast(float, v << 16); }
__device__ __forceinline__ float hi2f(uint v) { return __builtin_bit_cast(float, v & 0xFFFF0000u); }

// ---------------- graph prep: counting sort by destination ----------------

__global__ __launch_bounds__(128) void k_gstart2(const int* __restrict__ batch,
                                                 int* __restrict__ gstart, int* __restrict__ counts) {
  __shared__ int lb[NG + 1];
  int t = threadIdx.x;
  if (t <= NG) {                      // first index with batch[i] >= t (batch is sorted)
    int lo = 0, hi = NN;
    while (lo < hi) { int mid = (lo + hi) >> 1; if (batch[mid] < t) lo = mid + 1; else hi = mid; }
    lb[t] = lo;
  }
  __syncthreads();
  if (t < NG) { gstart[t] = lb[t]; counts[t] = lb[t + 1] - lb[t]; }
  if (t == 0) gstart[NG] = NN;
}

__global__ __launch_bounds__(256) void k_hist(const int* __restrict__ ei, int* __restrict__ ghist) {
  __shared__ int h[NB];
  int t = threadIdx.x, blk = blockIdx.x;
  for (int i = t; i < NB; i += 256) h[i] = 0;
  __syncthreads();
  int e0 = blk * EPB, e1 = min(NE, e0 + EPB);
  for (int e = e0 + t; e < e1; e += 256) atomicAdd(&h[ei[NE + e] >> 7], 1);
  __syncthreads();
  for (int i = t; i < NB; i += 256) ghist[i * NBLK + blk] = h[i];
}

__global__ __launch_bounds__(256) void k_scan1g(int* __restrict__ data, int* __restrict__ bsums) {
  __shared__ int sh[256];
  int t = threadIdx.x;
  int base = blockIdx.x * 1024 + t * 4;
  int4 v = *reinterpret_cast<const int4*>(data + base);
  int s = v.x + v.y + v.z + v.w;
  sh[t] = s;
  __syncthreads();
  for (int o = 1; o < 256; o <<= 1) {
    int x = (t >= o) ? sh[t - o] : 0;
    __syncthreads();
    sh[t] += x;
    __syncthreads();
  }
  int ex = sh[t] - s;
  int4 o4;
  o4.x = ex; o4.y = ex + v.x; o4.z = ex + v.x + v.y; o4.w = ex + v.x + v.y + v.z;
  *reinterpret_cast<int4*>(data + base) = o4;
  if (t == 255) bsums[blockIdx.x] = sh[255];
}

__global__ __launch_bounds__(512) void k_scan2(int* bsums, int nb) {
  __shared__ int sh[512];
  int t = threadIdx.x;
  int v = (t < nb) ? bsums[t] : 0;
  sh[t] = v;
  __syncthreads();
  for (int o = 1; o < 512; o <<= 1) {
    int x = (t >= o) ? sh[t - o] : 0;
    __syncthreads();
    sh[t] += x;
    __syncthreads();
  }
  if (t < nb) bsums[t] = sh[t] - v;   // exclusive
}

__global__ __launch_bounds__(256) void k_scan3g(int* __restrict__ data, const int* __restrict__ bsums) {
  int t = threadIdx.x;
  int base = blockIdx.x * 1024 + t * 4;
  int add = bsums[blockIdx.x];
  int4 v = *reinterpret_cast<int4*>(data + base);
  v.x += add; v.y += add; v.z += add; v.w += add;
  *reinterpret_cast<int4*>(data + base) = v;
}

__global__ __launch_bounds__(256) void k_scatter(const int* __restrict__ ei, const int* __restrict__ ghist,
                                                 int2* __restrict__ tmp) {
  __shared__ int cur[NB];
  int t = threadIdx.x, blk = blockIdx.x;
  for (int i = t; i < NB; i += 256) cur[i] = ghist[i * NBLK + blk];
  __syncthreads();
  int e0 = blk * EPB, e1 = min(NE, e0 + EPB);
  for (int e = e0 + t; e < e1; e += 256) {
    int d = ei[NE + e], s = ei[e];
    int p = atomicAdd(&cur[d >> 7], 1);   // LDS atomic (fast, block-local)
    tmp[p] = make_int2(d, s);
  }
}

// fine bucket: per-node deg/offs/dis + CSR (unsorted rows — fast version)
__global__ __launch_bounds__(256) void k_fine(const int2* __restrict__ tmp, const int* __restrict__ ghist,
                                              int* __restrict__ deg, int* __restrict__ offs,
                                              float* __restrict__ dis, int* __restrict__ csr) {
  __shared__ int fh[128], fsc[128], fc[128];
  int b = blockIdx.x, t = threadIdx.x;
  int bs = ghist[b * NBLK];
  int be = (b + 1 < NB) ? ghist[(b + 1) * NBLK] : NE;
  if (t < 128) fh[t] = 0;
  __syncthreads();
  for (int e = bs + t; e < be; e += 256) atomicAdd(&fh[tmp[e].x & 127], 1);
  __syncthreads();
  if (t < 128) fsc[t] = fh[t];
  __syncthreads();
  for (int o = 1; o < 128; o <<= 1) {
    int x = 0;
    if (t < 128 && t >= o) x = fsc[t - o];
    __syncthreads();
    if (t < 128) fsc[t] += x;
    __syncthreads();
  }
  if (t < 128) {
    int ex = fsc[t] - fh[t];
    int node = b * 128 + t;
    fc[t] = bs + ex;
    if (node < NN) {
      deg[node] = fh[t];
      offs[node] = bs + ex;
      dis[node] = rsqrtf((float)(fh[t] + 1));   // +1 self-loop
    }
  }
  __syncthreads();
  for (int e = bs + t; e < be; e += 256) {
    int2 ds = tmp[e];
    int p = atomicAdd(&fc[ds.x & 127], 1);
    csr[p] = ds.y;
  }
}

// ---------------- W pre-pack: fragment-major bf16 B-operand (both layers) ----------------
__global__ __launch_bounds__(256) void k_prepw(const float* __restrict__ W1, ushort* __restrict__ WF1,
                                               const float* __restrict__ W2, ushort* __restrict__ WF2) {
  int tt = blockIdx.x * 256 + threadIdx.x;
  if (tt >= 4096) return;
  const float* W = (tt < 2048) ? W1 : W2;
  ushort* WF = (tt < 2048) ? WF1 : WF2;
  int t = tt & 2047;
  int lane = t & 63, nk = t >> 6;
  int n = nk >> 2, ks = nk & 3;
  int col = n * 16 + (lane & 15);
  int k0 = ks * 32 + (lane >> 4) * 8;
#pragma unroll
  for (int j = 0; j < 8; ++j) WF[(size_t)t * 8 + j] = f2b(W[(k0 + j) * NH + col]);
}

// ---------------- MFMA GEMM: hs_fp8 = (norm?(X) @ W) * dis ----------------
// Wave = 16 rows x 128 cols. Block = 4 waves = 64 rows. Epilogue: fp8 via LDS, coalesced u64 out.
template <bool NORM>
__global__ __launch_bounds__(256) void k_gemm(const void* __restrict__ Xv, const ushort* __restrict__ WF,
                                              const float* __restrict__ dis, const int* __restrict__ batch,
                                              const float* __restrict__ Aaff, const float* __restrict__ Baff,
                                              uchar* __restrict__ out) {
  __shared__ uint sds[4][512];            // per-wave 2KB fp8 staging
  int t = threadIdx.x;
  int w = t >> 6, lane = t & 63;
  int r0 = blockIdx.x * 64 + w * 16;
  int arow = r0 + (lane & 15);
  int khi = lane >> 4;                    // 0..3
  int arowc = (arow < NN) ? arow : (NN - 1);

  f32x4 acc[8];
#pragma unroll
  for (int n = 0; n < 8; ++n) acc[n] = (f32x4){0.f, 0.f, 0.f, 0.f};

  int g = 0;
  if (NORM) g = batch[arowc];
  const bf16x8* WFv = reinterpret_cast<const bf16x8*>(WF);

#pragma unroll
  for (int ks = 0; ks < 4; ++ks) {
    int k0 = ks * 32 + khi * 8;
    bf16x8 a;
    if (!NORM) {
      const float* X = (const float*)Xv;
      float4 x0 = *reinterpret_cast<const float4*>(X + (size_t)arowc * NH + k0);
      float4 x1 = *reinterpret_cast<const float4*>(X + (size_t)arowc * NH + k0 + 4);
      a[0] = (short)f2b(x0.x); a[1] = (short)f2b(x0.y); a[2] = (short)f2b(x0.z); a[3] = (short)f2b(x0.w);
      a[4] = (short)f2b(x1.x); a[5] = (short)f2b(x1.y); a[6] = (short)f2b(x1.z); a[7] = (short)f2b(x1.w);
    } else {
      const ushort* X = (const ushort*)Xv;   // flat bf16 [node][128]
      bf16x8 xr = *reinterpret_cast<const bf16x8*>(X + (size_t)arowc * NH + k0);
      float4 A0 = *reinterpret_cast<const float4*>(Aaff + g * NH + k0);
      float4 A1 = *reinterpret_cast<const float4*>(Aaff + g * NH + k0 + 4);
      float4 B0 = *reinterpret_cast<const float4*>(Baff + g * NH + k0);
      float4 B1 = *reinterpret_cast<const float4*>(Baff + g * NH + k0 + 4);
      a[0] = (short)f2b(fmaf(A0.x, b2f((ushort)xr[0]), B0.x));
      a[1] = (short)f2b(fmaf(A0.y, b2f((ushort)xr[1]), B0.y));
      a[2] = (short)f2b(fmaf(A0.z, b2f((ushort)xr[2]), B0.z));
      a[3] = (short)f2b(fmaf(A0.w, b2f((ushort)xr[3]), B0.w));
      a[4] = (short)f2b(fmaf(A1.x, b2f((ushort)xr[4]), B1.x));
      a[5] = (short)f2b(fmaf(A1.y, b2f((ushort)xr[5]), B1.y));
      a[6] = (short)f2b(fmaf(A1.z, b2f((ushort)xr[6]), B1.z));
      a[7] = (short)f2b(fmaf(A1.w, b2f((ushort)xr[7]), B1.w));
    }
#pragma unroll
    for (int n = 0; n < 8; ++n) {
      bf16x8 b = WFv[(n * 4 + ks) * 64 + lane];
      acc[n] = __builtin_amdgcn_mfma_f32_16x16x32_bf16(a, b, acc[n], 0, 0, 0);
    }
  }

  // epilogue: D (col = n*16 + (lane&15), row = khi*4 + reg) -> fp8 bytes in LDS
  int colb = lane & 15;
  uchar* sb = (uchar*)sds[w];
#pragma unroll
  for (int reg = 0; reg < 4; ++reg) {
    int row = khi * 4 + reg;
    int grow = r0 + row;
    float d = (grow < NN) ? dis[grow] : 0.f;
#pragma unroll
    for (int n = 0; n < 8; n += 2) {
      int p2 = __builtin_amdgcn_cvt_pk_fp8_f32(acc[n][reg] * d, acc[n + 1][reg] * d, 0, false);
      sb[row * 128 + n * 16 + colb] = (uchar)(p2 & 0xFF);
      sb[row * 128 + (n + 1) * 16 + colb] = (uchar)((p2 >> 8) & 0xFF);
    }
  }
  __syncthreads();
  // coalesced write-out: 16 rows x 128B contiguous per wave
  const u64* ss = (const u64*)sds[w];
  u64* gout = (u64*)(out + (size_t)r0 * 128);
#pragma unroll
  for (int it = 0; it < 4; ++it) {
    int idx = it * 64 + lane;
    int row = idx >> 4;
    if (r0 + row < NN) __builtin_nontemporal_store(ss[idx], &gout[idx]);
  }
}

// ---------------- aggregation: t = relu(dis[i]*(hs[i]+sum_src hs[src]) + b) ----------------
// fp8 gather source (128 B/row), 1 node per wave, 64 lanes x ushort (2 fp8), bf16 out.
__global__ __launch_bounds__(256) void k_agg(const ushort* __restrict__ hf8, const int* __restrict__ offs,
                                             const int* __restrict__ deg, const int* __restrict__ csr,
                                             const float* __restrict__ dis, const float* __restrict__ bias,
                                             uint* __restrict__ outb) {
  int w = threadIdx.x >> 6, lane = threadIdx.x & 63;
  int node = blockIdx.x * 4 + w;
  if (node >= NN) return;
  float2 b2 = reinterpret_cast<const float2*>(bias)[lane];   // feats 2*lane, 2*lane+1
  f32x2 sv = __builtin_amdgcn_cvt_pk_f32_fp8((int)hf8[(size_t)node * 64 + lane], false);
  float a0 = sv[0], a1 = sv[1];
  int beg = __builtin_nontemporal_load(offs + node);
  int cnt = __builtin_nontemporal_load(deg + node);
  int i = 0;
  for (; i + 8 <= cnt; i += 8) {
    int s0 = __builtin_nontemporal_load(csr + beg + i + 0);
    int s1 = __builtin_nontemporal_load(csr + beg + i + 1);
    int s2 = __builtin_nontemporal_load(csr + beg + i + 2);
    int s3 = __builtin_nontemporal_load(csr + beg + i + 3);
    int s4 = __builtin_nontemporal_load(csr + beg + i + 4);
    int s5 = __builtin_nontemporal_load(csr + beg + i + 5);
    int s6 = __builtin_nontemporal_load(csr + beg + i + 6);
    int s7 = __builtin_nontemporal_load(csr + beg + i + 7);
    ushort v0 = hf8[(size_t)s0 * 64 + lane];
    ushort v1 = hf8[(size_t)s1 * 64 + lane];
    ushort v2 = hf8[(size_t)s2 * 64 + lane];
    ushort v3 = hf8[(size_t)s3 * 64 + lane];
    ushort v4 = hf8[(size_t)s4 * 64 + lane];
    ushort v5 = hf8[(size_t)s5 * 64 + lane];
    ushort v6 = hf8[(size_t)s6 * 64 + lane];
    ushort v7 = hf8[(size_t)s7 * 64 + lane];
    f32x2 f0 = __builtin_amdgcn_cvt_pk_f32_fp8((int)v0, false);
    f32x2 f1 = __builtin_amdgcn_cvt_pk_f32_fp8((int)v1, false);
    f32x2 f2 = __builtin_amdgcn_cvt_pk_f32_fp8((int)v2, false);
    f32x2 f3 = __builtin_amdgcn_cvt_pk_f32_fp8((int)v3, false);
    f32x2 f4 = __builtin_amdgcn_cvt_pk_f32_fp8((int)v4, false);
    f32x2 f5 = __builtin_amdgcn_cvt_pk_f32_fp8((int)v5, false);
    f32x2 f6 = __builtin_amdgcn_cvt_pk_f32_fp8((int)v6, false);
    f32x2 f7 = __builtin_amdgcn_cvt_pk_f32_fp8((int)v7, false);
    a0 += f0[0] + f1[0] + f2[0] + f3[0] + f4[0] + f5[0] + f6[0] + f7[0];
    a1 += f0[1] + f1[1] + f2[1] + f3[1] + f4[1] + f5[1] + f6[1] + f7[1];
  }
  for (; i < cnt; ++i) {
    int s = __builtin_nontemporal_load(csr + beg + i);
    f32x2 f = __builtin_amdgcn_cvt_pk_f32_fp8((int)hf8[(size_t)s * 64 + lane], false);
    a0 += f[0];
    a1 += f[1];
  }
  float d = dis[node];
  float o0 = fmaxf(fmaf(d, a0, b2.x), 0.f);
  float o1 = fmaxf(fmaf(d, a1, b2.y), 0.f);
  uint pk = (uint)f2b(o0) | ((uint)f2b(o1) << 16);
  __builtin_nontemporal_store(pk, &outb[(size_t)node * 64 + lane]);
}

// ---------------- GraphNorm stats: per-(g,f) sum & sumsq partials (no atomics) ----------------
__global__ __launch_bounds__(256) void k_stats(const uint* __restrict__ t2, const int* __restrict__ gstart,
                                               float* __restrict__ acc) {
  int g = blockIdx.x >> 4, s = blockIdx.x & 15;
  int beg = gstart[g], end = gstart[g + 1];
  int f2 = threadIdx.x & 63, q = threadIdx.x >> 6;   // 4 row-groups
  float sx = 0.f, qx = 0.f, sy = 0.f, qy = 0.f;
  for (int n = beg + s * 4 + q; n < end; n += 64) {
    uint v = t2[(size_t)n * 64 + f2];
    float a = lo2f(v), b = hi2f(v);
    sx += a; qx = fmaf(a, a, qx);
    sy += b; qy = fmaf(b, b, qy);
  }
  __shared__ float sh[4][256];
  sh[0][threadIdx.x] = sx; sh[1][threadIdx.x] = qx;
  sh[2][threadIdx.x] = sy; sh[3][threadIdx.x] = qy;
  __syncthreads();
  if (q == 0) {
#pragma unroll
    for (int qq = 1; qq < 4; ++qq) {
      int idx = (qq << 6) | f2;
      sx += sh[0][idx]; qx += sh[1][idx];
      sy += sh[2][idx]; qy += sh[3][idx];
    }
    int f = f2 * 2;
    float* dst = acc + (size_t)(s * NG + g) * 2 * NH;
    dst[f] = sx; dst[f + 1] = sy;
    dst[NH + f] = qx; dst[NH + f + 1] = qy;
  }
}

__global__ __launch_bounds__(128) void k_fin1(const float* __restrict__ acc, const int* __restrict__ counts,
                                              const float* __restrict__ gw, const float* __restrict__ gb,
                                              const float* __restrict__ ga,
                                              float* __restrict__ Aaff, float* __restrict__ Baff) {
  int g = blockIdx.x, f = threadIdx.x;
  float sum = 0.f, sq = 0.f;
#pragma unroll 4
  for (int s = 0; s < 16; ++s) {
    const float* d = acc + (size_t)(s * NG + g) * 2 * NH;
    sum += d[f];
    sq += d[NH + f];
  }
  float cnt = fmaxf((float)counts[g], 1.f);
  float m = sum / cnt;
  float ex2 = sq / cnt;
  float a = ga[f];
  float var = ex2 - 2.f * a * m * m + a * a * m * m;
  float rstd = rsqrtf(var + EPSV);
  float A = gw[f] * rstd;
  Aaff[g * NH + f] = A;
  Baff[g * NH + f] = gb[f] - A * a * m;
}

// fused layer-2 finalize + classifier head + softmax
__global__ __launch_bounds__(128) void k_fin2head(const float* __restrict__ acc, const int* __restrict__ counts,
                                                  const float* __restrict__ gw, const float* __restrict__ gb,
                                                  const float* __restrict__ ga, const float* __restrict__ Wc,
                                                  const float* __restrict__ bc, float* __restrict__ outp) {
  __shared__ float pool[NH];
  __shared__ float lg[NC];
  int g = blockIdx.x, f = threadIdx.x;
  float sum = 0.f, sq = 0.f;
#pragma unroll 4
  for (int s = 0; s < 16; ++s) {
    const float* d = acc + (size_t)(s * NG + g) * 2 * NH;
    sum += d[f];
    sq += d[NH + f];
  }
  float cnt = fmaxf((float)counts[g], 1.f);
  float m = sum / cnt;
  float ex2 = sq / cnt;
  float a = ga[f];
  float var = ex2 - 2.f * a * m * m + a * a * m * m;
  float rstd = rsqrtf(var + EPSV);
  pool[f] = gw[f] * rstd * (m - a * m) + gb[f];
  __syncthreads();
  if (f < NC) {
    float s = bc[f];
    for (int h = 0; h < NH; ++h) s = fmaf(pool[h], Wc[h * NC + f], s);
    lg[f] = s;
  }
  __syncthreads();
  if (f == 0) {
    float mx = lg[0];
    for (int c = 1; c < NC; ++c) mx = fmaxf(mx, lg[c]);
    float ex[NC];
    float ssum = 0.f;
    for (int c = 0; c < NC; ++c) { ex[c] = __expf(lg[c] - mx); ssum += ex[c]; }
    float inv = 1.f / ssum;
    for (int c = 0; c < NC; ++c) outp[g * NC + c] = ex[c] * inv;
  }
}

// ---------------- launch ----------------
extern "C" void kernel_launch(void* const* d_in, const int* in_sizes, int n_in,
                              void* d_out, int out_size, void* d_ws, size_t ws_size,
                              hipStream_t stream) {
  const float* x   = (const float*)d_in[0];
  const int*   ei  = (const int*)d_in[1];
  const int*   bat = (const int*)d_in[2];
  const float* W1  = (const float*)d_in[3];
  const float* b1  = (const float*)d_in[4];
  const float* gw1 = (const float*)d_in[5];
  const float* gb1 = (const float*)d_in[6];
  const float* ga1 = (const float*)d_in[7];
  const float* W2  = (const float*)d_in[8];
  const float* b2  = (const float*)d_in[9];
  const float* gw2 = (const float*)d_in[10];
  const float* gb2 = (const float*)d_in[11];
  const float* ga2 = (const float*)d_in[12];
  const float* Wc  = (const float*)d_in[13];
  const float* bc  = (const float*)d_in[14];
  float* outp = (float*)d_out;

  char* ws = (char*)d_ws;
  size_t off = 0;
  auto alloc = [&](size_t b) { size_t p = off; off += (b + 255) & ~(size_t)255; return p; };
  int*    deg     = (int*)(ws + alloc((size_t)NN * 4));
  float*  dis     = (float*)(ws + alloc((size_t)NN * 4));
  int*    counts  = (int*)(ws + alloc(NG * 4));
  int*    gstart  = (int*)(ws + alloc((NG + 1) * 4));
  int*    offs    = (int*)(ws + alloc((size_t)NN * 4));
  int*    bsums   = (int*)(ws + alloc(512 * 4));
  int*    csr     = (int*)(ws + alloc((size_t)NE * 4));
  float*  statacc = (float*)(ws + alloc((size_t)16 * NG * 2 * NH * 4));   // 1 MB partials
  float*  Aaff    = (float*)(ws + alloc((size_t)NG * NH * 4));
  float*  Baff    = (float*)(ws + alloc((size_t)NG * NH * 4));
  ushort* WF1     = (ushort*)(ws + alloc((size_t)2048 * 8 * 2));
  ushort* WF2     = (ushort*)(ws + alloc((size_t)2048 * 8 * 2));
  uchar*  bufA    = (uchar*)(ws + alloc((size_t)NN * NH));       // fp8 gather source, 12.8 MB
  ushort* bufB    = (ushort*)(ws + alloc((size_t)NN * NH * 2));  // bf16 agg output, 25.6 MB
  // sort temps alias bufB (dead until first k_agg write): 12.8 + 1.6 MB <= 25.6 MB
  int2* tmp   = (int2*)bufB;
  int*  ghist = (int*)((char*)bufB + (((size_t)NE * 8 + 255) & ~(size_t)255));
  (void)ws_size; (void)in_sizes; (void)n_in; (void)out_size;

  // prep: counts/gstart via binary search (batch sorted); CSR via counting sort
  k_gstart2<<<1, 128, 0, stream>>>(bat, gstart, counts);
  k_hist<<<NBLK, 256, 0, stream>>>(ei, ghist);
  k_scan1g<<<NSB, 256, 0, stream>>>(ghist, bsums);
  k_scan2<<<1, 512, 0, stream>>>(bsums, NSB);
  k_scan3g<<<NSB, 256, 0, stream>>>(ghist, bsums);
  k_scatter<<<NBLK, 256, 0, stream>>>(ei, ghist, tmp);
  k_fine<<<NB, 256, 0, stream>>>(tmp, ghist, deg, offs, dis, csr);
  k_prepw<<<16, 256, 0, stream>>>(W1, WF1, W2, WF2);

  int gemm_grid = (NN + 63) / 64;   // 1563
  int agg_grid  = (NN + 3) / 4;     // 25000

  // layer 1
  k_gemm<false><<<gemm_grid, 256, 0, stream>>>(x, WF1, dis, bat, nullptr, nullptr, bufA);
  k_agg<<<agg_grid, 256, 0, stream>>>((const ushort*)bufA, offs, deg, csr, dis, b1, (uint*)bufB);
  k_stats<<<NG * 16, 256, 0, stream>>>((const uint*)bufB, gstart, statacc);
  k_fin1<<<NG, 128, 0, stream>>>(statacc, counts, gw1, gb1, ga1, Aaff, Baff);

  // layer 2 (norm fused into GEMM A-fragment load)
  k_gemm<true><<<gemm_grid, 256, 0, stream>>>(bufB, WF2, dis, bat, Aaff, Baff, bufA);
  k_agg<<<agg_grid, 256, 0, stream>>>((const ushort*)bufA, offs, deg, csr, dis, b2, (uint*)bufB);
  k_stats<<<NG * 16, 256, 0, stream>>>((const uint*)bufB, gstart, statacc);
  k_fin2head<<<NG, 128, 0, stream>>>(statacc, counts, gw2, gb2, ga2, Wc, bc, outp);
}

// Round 9
// 295.426 us; speedup vs baseline: 1.4305x; 1.0494x over previous
//
#include <hip/hip_runtime.h>
#include <cstdint>

#define NN 100000
#define NE 1600000
#define NG 64
#define NH 128
#define NC 10
#define EPSV 1e-5f

#define NB 782                       // (NN+127)>>7 coarse buckets (128 nodes each)
#define NBLK 512                     // histogram/scatter blocks
#define EPB ((NE + NBLK - 1) / NBLK) // 3125 edges per block
#define NSCAN (NB * NBLK)            // 400384, divisible by 1024
#define NSB (NSCAN / 1024)           // 391 scan blocks

typedef __attribute__((ext_vector_type(8))) short bf16x8;
typedef __attribute__((ext_vector_type(4))) float f32x4;
typedef __attribute__((ext_vector_type(2))) float f32x2;
typedef unsigned long long u64;
typedef unsigned char uchar;

__device__ __forceinline__ ushort f2b(float f) {
  uint u = __builtin_bit_cast(uint, f);
  u = (u + 0x7FFFu + ((u >> 16) & 1u)) >> 16;
  return (ushort)u;
}
__device__ __forceinline__ float b2f(ushort h) {
  return __builtin_bit_cast(float, ((uint)h) << 16);
}
__device__ __forceinline__ float lo2f(uint v) { return __builtin_bit_cast(float, v << 16); }
__device__ __forceinline__ float hi2f(uint v) { return __builtin_bit_cast(float, v & 0xFFFF0000u); }

// ---------------- graph prep: counting sort by destination ----------------

__global__ __launch_bounds__(128) void k_gstart2(const int* __restrict__ batch,
                                                 int* __restrict__ gstart, int* __restrict__ counts) {
  __shared__ int lb[NG + 1];
  int t = threadIdx.x;
  if (t <= NG) {                      // first index with batch[i] >= t (batch is sorted)
    int lo = 0, hi = NN;
    while (lo < hi) { int mid = (lo + hi) >> 1; if (batch[mid] < t) lo = mid + 1; else hi = mid; }
    lb[t] = lo;
  }
  __syncthreads();
  if (t < NG) { gstart[t] = lb[t]; counts[t] = lb[t + 1] - lb[t]; }
  if (t == 0) gstart[NG] = NN;
}

__global__ __launch_bounds__(256) void k_hist(const int* __restrict__ ei, int* __restrict__ ghist) {
  __shared__ int h[NB];
  int t = threadIdx.x, blk = blockIdx.x;
  for (int i = t; i < NB; i += 256) h[i] = 0;
  __syncthreads();
  int e0 = blk * EPB, e1 = min(NE, e0 + EPB);
  for (int e = e0 + t; e < e1; e += 256) atomicAdd(&h[ei[NE + e] >> 7], 1);
  __syncthreads();
  for (int i = t; i < NB; i += 256) ghist[i * NBLK + blk] = h[i];
}

__global__ __launch_bounds__(256) void k_scan1g(int* __restrict__ data, int* __restrict__ bsums) {
  __shared__ int sh[256];
  int t = threadIdx.x;
  int base = blockIdx.x * 1024 + t * 4;
  int4 v = *reinterpret_cast<const int4*>(data + base);
  int s = v.x + v.y + v.z + v.w;
  sh[t] = s;
  __syncthreads();
  for (int o = 1; o < 256; o <<= 1) {
    int x = (t >= o) ? sh[t - o] : 0;
    __syncthreads();
    sh[t] += x;
    __syncthreads();
  }
  int ex = sh[t] - s;
  int4 o4;
  o4.x = ex; o4.y = ex + v.x; o4.z = ex + v.x + v.y; o4.w = ex + v.x + v.y + v.z;
  *reinterpret_cast<int4*>(data + base) = o4;
  if (t == 255) bsums[blockIdx.x] = sh[255];
}

__global__ __launch_bounds__(512) void k_scan2(int* bsums, int nb) {
  __shared__ int sh[512];
  int t = threadIdx.x;
  int v = (t < nb) ? bsums[t] : 0;
  sh[t] = v;
  __syncthreads();
  for (int o = 1; o < 512; o <<= 1) {
    int x = (t >= o) ? sh[t - o] : 0;
    __syncthreads();
    sh[t] += x;
    __syncthreads();
  }
  if (t < nb) bsums[t] = sh[t] - v;   // exclusive
}

__global__ __launch_bounds__(256) void k_scan3g(int* __restrict__ data, const int* __restrict__ bsums) {
  int t = threadIdx.x;
  int base = blockIdx.x * 1024 + t * 4;
  int add = bsums[blockIdx.x];
  int4 v = *reinterpret_cast<int4*>(data + base);
  v.x += add; v.y += add; v.z += add; v.w += add;
  *reinterpret_cast<int4*>(data + base) = v;
}

__global__ __launch_bounds__(256) void k_scatter(const int* __restrict__ ei, const int* __restrict__ ghist,
                                                 int2* __restrict__ tmp) {
  __shared__ int cur[NB];
  int t = threadIdx.x, blk = blockIdx.x;
  for (int i = t; i < NB; i += 256) cur[i] = ghist[i * NBLK + blk];
  __syncthreads();
  int e0 = blk * EPB, e1 = min(NE, e0 + EPB);
  for (int e = e0 + t; e < e1; e += 256) {
    int d = ei[NE + e], s = ei[e];
    int p = atomicAdd(&cur[d >> 7], 1);   // LDS atomic (fast, block-local)
    tmp[p] = make_int2(d, s);
  }
}

// fine bucket: per-node deg/offs/dis + CSR (unsorted rows — fast version)
__global__ __launch_bounds__(256) void k_fine(const int2* __restrict__ tmp, const int* __restrict__ ghist,
                                              int* __restrict__ deg, int* __restrict__ offs,
                                              float* __restrict__ dis, int* __restrict__ csr) {
  __shared__ int fh[128], fsc[128], fc[128];
  int b = blockIdx.x, t = threadIdx.x;
  int bs = ghist[b * NBLK];
  int be = (b + 1 < NB) ? ghist[(b + 1) * NBLK] : NE;
  if (t < 128) fh[t] = 0;
  __syncthreads();
  for (int e = bs + t; e < be; e += 256) atomicAdd(&fh[tmp[e].x & 127], 1);
  __syncthreads();
  if (t < 128) fsc[t] = fh[t];
  __syncthreads();
  for (int o = 1; o < 128; o <<= 1) {
    int x = 0;
    if (t < 128 && t >= o) x = fsc[t - o];
    __syncthreads();
    if (t < 128) fsc[t] += x;
    __syncthreads();
  }
  if (t < 128) {
    int ex = fsc[t] - fh[t];
    int node = b * 128 + t;
    fc[t] = bs + ex;
    if (node < NN) {
      deg[node] = fh[t];
      offs[node] = bs + ex;
      dis[node] = rsqrtf((float)(fh[t] + 1));   // +1 self-loop
    }
  }
  __syncthreads();
  for (int e = bs + t; e < be; e += 256) {
    int2 ds = tmp[e];
    int p = atomicAdd(&fc[ds.x & 127], 1);
    csr[p] = ds.y;
  }
}

// ---------------- W pre-pack: fragment-major bf16 B-operand (both layers) ----------------
__global__ __launch_bounds__(256) void k_prepw(const float* __restrict__ W1, ushort* __restrict__ WF1,
                                               const float* __restrict__ W2, ushort* __restrict__ WF2) {
  int tt = blockIdx.x * 256 + threadIdx.x;
  if (tt >= 4096) return;
  const float* W = (tt < 2048) ? W1 : W2;
  ushort* WF = (tt < 2048) ? WF1 : WF2;
  int t = tt & 2047;
  int lane = t & 63, nk = t >> 6;
  int n = nk >> 2, ks = nk & 3;
  int col = n * 16 + (lane & 15);
  int k0 = ks * 32 + (lane >> 4) * 8;
#pragma unroll
  for (int j = 0; j < 8; ++j) WF[(size_t)t * 8 + j] = f2b(W[(k0 + j) * NH + col]);
}

// ---------------- MFMA GEMM: hs_fp8 = (norm?(X) @ W) * dis ----------------
// Wave = 16 rows x 128 cols. Block = 4 waves = 64 rows. Epilogue: fp8 via LDS, coalesced u64 out.
template <bool NORM>
__global__ __launch_bounds__(256) void k_gemm(const void* __restrict__ Xv, const ushort* __restrict__ WF,
                                              const float* __restrict__ dis, const int* __restrict__ batch,
                                              const float* __restrict__ Aaff, const float* __restrict__ Baff,
                                              uchar* __restrict__ out) {
  __shared__ uint sds[4][512];            // per-wave 2KB fp8 staging
  int t = threadIdx.x;
  int w = t >> 6, lane = t & 63;
  int r0 = blockIdx.x * 64 + w * 16;
  int arow = r0 + (lane & 15);
  int khi = lane >> 4;                    // 0..3
  int arowc = (arow < NN) ? arow : (NN - 1);

  f32x4 acc[8];
#pragma unroll
  for (int n = 0; n < 8; ++n) acc[n] = (f32x4){0.f, 0.f, 0.f, 0.f};

  int g = 0;
  if (NORM) g = batch[arowc];
  const bf16x8* WFv = reinterpret_cast<const bf16x8*>(WF);

#pragma unroll
  for (int ks = 0; ks < 4; ++ks) {
    int k0 = ks * 32 + khi * 8;
    bf16x8 a;
    if (!NORM) {
      const float* X = (const float*)Xv;
      float4 x0 = *reinterpret_cast<const float4*>(X + (size_t)arowc * NH + k0);
      float4 x1 = *reinterpret_cast<const float4*>(X + (size_t)arowc * NH + k0 + 4);
      a[0] = (short)f2b(x0.x); a[1] = (short)f2b(x0.y); a[2] = (short)f2b(x0.z); a[3] = (short)f2b(x0.w);
      a[4] = (short)f2b(x1.x); a[5] = (short)f2b(x1.y); a[6] = (short)f2b(x1.z); a[7] = (short)f2b(x1.w);
    } else {
      const ushort* X = (const ushort*)Xv;   // flat bf16 [node][128]
      bf16x8 xr = *reinterpret_cast<const bf16x8*>(X + (size_t)arowc * NH + k0);
      float4 A0 = *reinterpret_cast<const float4*>(Aaff + g * NH + k0);
      float4 A1 = *reinterpret_cast<const float4*>(Aaff + g * NH + k0 + 4);
      float4 B0 = *reinterpret_cast<const float4*>(Baff + g * NH + k0);
      float4 B1 = *reinterpret_cast<const float4*>(Baff + g * NH + k0 + 4);
      a[0] = (short)f2b(fmaf(A0.x, b2f((ushort)xr[0]), B0.x));
      a[1] = (short)f2b(fmaf(A0.y, b2f((ushort)xr[1]), B0.y));
      a[2] = (short)f2b(fmaf(A0.z, b2f((ushort)xr[2]), B0.z));
      a[3] = (short)f2b(fmaf(A0.w, b2f((ushort)xr[3]), B0.w));
      a[4] = (short)f2b(fmaf(A1.x, b2f((ushort)xr[4]), B1.x));
      a[5] = (short)f2b(fmaf(A1.y, b2f((ushort)xr[5]), B1.y));
      a[6] = (short)f2b(fmaf(A1.z, b2f((ushort)xr[6]), B1.z));
      a[7] = (short)f2b(fmaf(A1.w, b2f((ushort)xr[7]), B1.w));
    }
#pragma unroll
    for (int n = 0; n < 8; ++n) {
      bf16x8 b = WFv[(n * 4 + ks) * 64 + lane];
      acc[n] = __builtin_amdgcn_mfma_f32_16x16x32_bf16(a, b, acc[n], 0, 0, 0);
    }
  }

  // epilogue: D (col = n*16 + (lane&15), row = khi*4 + reg) -> fp8 bytes in LDS
  int colb = lane & 15;
  uchar* sb = (uchar*)sds[w];
#pragma unroll
  for (int reg = 0; reg < 4; ++reg) {
    int row = khi * 4 + reg;
    int grow = r0 + row;
    float d = (grow < NN) ? dis[grow] : 0.f;
#pragma unroll
    for (int n = 0; n < 8; n += 2) {
      int p2 = __builtin_amdgcn_cvt_pk_fp8_f32(acc[n][reg] * d, acc[n + 1][reg] * d, 0, false);
      sb[row * 128 + n * 16 + colb] = (uchar)(p2 & 0xFF);
      sb[row * 128 + (n + 1) * 16 + colb] = (uchar)((p2 >> 8) & 0xFF);
    }
  }
  __syncthreads();
  // coalesced write-out: 16 rows x 128B contiguous per wave
  const u64* ss = (const u64*)sds[w];
  u64* gout = (u64*)(out + (size_t)r0 * 128);
#pragma unroll
  for (int it = 0; it < 4; ++it) {
    int idx = it * 64 + lane;
    int row = idx >> 4;
    if (r0 + row < NN) __builtin_nontemporal_store(ss[idx], &gout[idx]);
  }
}

// ---------------- aggregation: t = relu(dis[i]*(hs[i]+sum_src hs[src]) + b) ----------------
// fp8 source (128 B/row). 1 node/wave, TWO edges per wave-load: half = lane>>5 handles
// edges i+half; each lane loads a dword (4 fp8 feats). Cross-half combine via shfl_xor(32).
__global__ __launch_bounds__(256) void k_agg(const uint* __restrict__ hf8, const int* __restrict__ offs,
                                             const int* __restrict__ deg, const int* __restrict__ csr,
                                             const float* __restrict__ dis, const float* __restrict__ bias,
                                             u64* __restrict__ outb) {
  int w = threadIdx.x >> 6, lane = threadIdx.x & 63;
  int half = lane >> 5, sub = lane & 31;
  int node = blockIdx.x * 4 + w;
  if (node >= NN) return;
  float a0 = 0.f, a1 = 0.f, a2 = 0.f, a3 = 0.f;
  if (half == 0) {                        // self term counted once
    uint v = hf8[(size_t)node * 32 + sub];
    f32x2 fl = __builtin_amdgcn_cvt_pk_f32_fp8((int)v, false);
    f32x2 fh = __builtin_amdgcn_cvt_pk_f32_fp8((int)v, true);
    a0 = fl[0]; a1 = fl[1]; a2 = fh[0]; a3 = fh[1];
  }
  int beg = __builtin_nontemporal_load(offs + node);
  int cnt = __builtin_nontemporal_load(deg + node);
  int i = half;
  for (; i + 8 <= cnt; i += 8) {          // this half: edges i, i+2, i+4, i+6
    int s0 = __builtin_nontemporal_load(csr + beg + i);
    int s1 = __builtin_nontemporal_load(csr + beg + i + 2);
    int s2 = __builtin_nontemporal_load(csr + beg + i + 4);
    int s3 = __builtin_nontemporal_load(csr + beg + i + 6);
    uint v0 = hf8[(size_t)s0 * 32 + sub];
    uint v1 = hf8[(size_t)s1 * 32 + sub];
    uint v2 = hf8[(size_t)s2 * 32 + sub];
    uint v3 = hf8[(size_t)s3 * 32 + sub];
    f32x2 l0 = __builtin_amdgcn_cvt_pk_f32_fp8((int)v0, false);
    f32x2 h0 = __builtin_amdgcn_cvt_pk_f32_fp8((int)v0, true);
    f32x2 l1 = __builtin_amdgcn_cvt_pk_f32_fp8((int)v1, false);
    f32x2 h1 = __builtin_amdgcn_cvt_pk_f32_fp8((int)v1, true);
    f32x2 l2 = __builtin_amdgcn_cvt_pk_f32_fp8((int)v2, false);
    f32x2 h2 = __builtin_amdgcn_cvt_pk_f32_fp8((int)v2, true);
    f32x2 l3 = __builtin_amdgcn_cvt_pk_f32_fp8((int)v3, false);
    f32x2 h3 = __builtin_amdgcn_cvt_pk_f32_fp8((int)v3, true);
    a0 += l0[0] + l1[0] + l2[0] + l3[0];
    a1 += l0[1] + l1[1] + l2[1] + l3[1];
    a2 += h0[0] + h1[0] + h2[0] + h3[0];
    a3 += h0[1] + h1[1] + h2[1] + h3[1];
  }
  for (; i < cnt; i += 2) {
    int s = __builtin_nontemporal_load(csr + beg + i);
    uint v = hf8[(size_t)s * 32 + sub];
    f32x2 fl = __builtin_amdgcn_cvt_pk_f32_fp8((int)v, false);
    f32x2 fh = __builtin_amdgcn_cvt_pk_f32_fp8((int)v, true);
    a0 += fl[0]; a1 += fl[1]; a2 += fh[0]; a3 += fh[1];
  }
  // combine halves
  a0 += __shfl_xor(a0, 32);
  a1 += __shfl_xor(a1, 32);
  a2 += __shfl_xor(a2, 32);
  a3 += __shfl_xor(a3, 32);
  if (half == 0) {
    float d = dis[node];
    float4 b4 = reinterpret_cast<const float4*>(bias)[sub];
    float o0 = fmaxf(fmaf(d, a0, b4.x), 0.f);
    float o1 = fmaxf(fmaf(d, a1, b4.y), 0.f);
    float o2 = fmaxf(fmaf(d, a2, b4.z), 0.f);
    float o3 = fmaxf(fmaf(d, a3, b4.w), 0.f);
    u64 pk = (u64)((uint)f2b(o0) | ((uint)f2b(o1) << 16)) |
             ((u64)((uint)f2b(o2) | ((uint)f2b(o3) << 16)) << 32);
    __builtin_nontemporal_store(pk, &outb[(size_t)node * 32 + sub]);
  }
}

// ---------------- GraphNorm stats: per-(g,f) sum & sumsq partials (no atomics) ----------------
__global__ __launch_bounds__(256) void k_stats(const uint* __restrict__ t2, const int* __restrict__ gstart,
                                               float* __restrict__ acc) {
  int g = blockIdx.x >> 4, s = blockIdx.x & 15;
  int beg = gstart[g], end = gstart[g + 1];
  int f2 = threadIdx.x & 63, q = threadIdx.x >> 6;   // 4 row-groups
  float sx = 0.f, qx = 0.f, sy = 0.f, qy = 0.f;
  for (int n = beg + s * 4 + q; n < end; n += 64) {
    uint v = t2[(size_t)n * 64 + f2];
    float a = lo2f(v), b = hi2f(v);
    sx += a; qx = fmaf(a, a, qx);
    sy += b; qy = fmaf(b, b, qy);
  }
  __shared__ float sh[4][256];
  sh[0][threadIdx.x] = sx; sh[1][threadIdx.x] = qx;
  sh[2][threadIdx.x] = sy; sh[3][threadIdx.x] = qy;
  __syncthreads();
  if (q == 0) {
#pragma unroll
    for (int qq = 1; qq < 4; ++qq) {
      int idx = (qq << 6) | f2;
      sx += sh[0][idx]; qx += sh[1][idx];
      sy += sh[2][idx]; qy += sh[3][idx];
    }
    int f = f2 * 2;
    float* dst = acc + (size_t)(s * NG + g) * 2 * NH;
    dst[f] = sx; dst[f + 1] = sy;
    dst[NH + f] = qx; dst[NH + f + 1] = qy;
  }
}

__global__ __launch_bounds__(128) void k_fin1(const float* __restrict__ acc, const int* __restrict__ counts,
                                              const float* __restrict__ gw, const float* __restrict__ gb,
                                              const float* __restrict__ ga,
                                              float* __restrict__ Aaff, float* __restrict__ Baff) {
  int g = blockIdx.x, f = threadIdx.x;
  float sum = 0.f, sq = 0.f;
#pragma unroll 4
  for (int s = 0; s < 16; ++s) {
    const float* d = acc + (size_t)(s * NG + g) * 2 * NH;
    sum += d[f];
    sq += d[NH + f];
  }
  float cnt = fmaxf((float)counts[g], 1.f);
  float m = sum / cnt;
  float ex2 = sq / cnt;
  float a = ga[f];
  float var = ex2 - 2.f * a * m * m + a * a * m * m;
  float rstd = rsqrtf(var + EPSV);
  float A = gw[f] * rstd;
  Aaff[g * NH + f] = A;
  Baff[g * NH + f] = gb[f] - A * a * m;
}

// fused layer-2 finalize + classifier head + softmax
__global__ __launch_bounds__(128) void k_fin2head(const float* __restrict__ acc, const int* __restrict__ counts,
                                                  const float* __restrict__ gw, const float* __restrict__ gb,
                                                  const float* __restrict__ ga, const float* __restrict__ Wc,
                                                  const float* __restrict__ bc, float* __restrict__ outp) {
  __shared__ float pool[NH];
  __shared__ float lg[NC];
  int g = blockIdx.x, f = threadIdx.x;
  float sum = 0.f, sq = 0.f;
#pragma unroll 4
  for (int s = 0; s < 16; ++s) {
    const float* d = acc + (size_t)(s * NG + g) * 2 * NH;
    sum += d[f];
    sq += d[NH + f];
  }
  float cnt = fmaxf((float)counts[g], 1.f);
  float m = sum / cnt;
  float ex2 = sq / cnt;
  float a = ga[f];
  float var = ex2 - 2.f * a * m * m + a * a * m * m;
  float rstd = rsqrtf(var + EPSV);
  pool[f] = gw[f] * rstd * (m - a * m) + gb[f];
  __syncthreads();
  if (f < NC) {
    float s = bc[f];
    for (int h = 0; h < NH; ++h) s = fmaf(pool[h], Wc[h * NC + f], s);
    lg[f] = s;
  }
  __syncthreads();
  if (f == 0) {
    float mx = lg[0];
    for (int c = 1; c < NC; ++c) mx = fmaxf(mx, lg[c]);
    float ex[NC];
    float ssum = 0.f;
    for (int c = 0; c < NC; ++c) { ex[c] = __expf(lg[c] - mx); ssum += ex[c]; }
    float inv = 1.f / ssum;
    for (int c = 0; c < NC; ++c) outp[g * NC + c] = ex[c] * inv;
  }
}

// ---------------- launch ----------------
extern "C" void kernel_launch(void* const* d_in, const int* in_sizes, int n_in,
                              void* d_out, int out_size, void* d_ws, size_t ws_size,
                              hipStream_t stream) {
  const float* x   = (const float*)d_in[0];
  const int*   ei  = (const int*)d_in[1];
  const int*   bat = (const int*)d_in[2];
  const float* W1  = (const float*)d_in[3];
  const float* b1  = (const float*)d_in[4];
  const float* gw1 = (const float*)d_in[5];
  const float* gb1 = (const float*)d_in[6];
  const float* ga1 = (const float*)d_in[7];
  const float* W2  = (const float*)d_in[8];
  const float* b2  = (const float*)d_in[9];
  const float* gw2 = (const float*)d_in[10];
  const float* gb2 = (const float*)d_in[11];
  const float* ga2 = (const float*)d_in[12];
  const float* Wc  = (const float*)d_in[13];
  const float* bc  = (const float*)d_in[14];
  float* outp = (float*)d_out;

  char* ws = (char*)d_ws;
  size_t off = 0;
  auto alloc = [&](size_t b) { size_t p = off; off += (b + 255) & ~(size_t)255; return p; };
  int*    deg     = (int*)(ws + alloc((size_t)NN * 4));
  float*  dis     = (float*)(ws + alloc((size_t)NN * 4));
  int*    counts  = (int*)(ws + alloc(NG * 4));
  int*    gstart  = (int*)(ws + alloc((NG + 1) * 4));
  int*    offs    = (int*)(ws + alloc((size_t)NN * 4));
  int*    bsums   = (int*)(ws + alloc(512 * 4));
  int*    csr     = (int*)(ws + alloc((size_t)NE * 4));
  float*  statacc = (float*)(ws + alloc((size_t)16 * NG * 2 * NH * 4));   // 1 MB partials
  float*  Aaff    = (float*)(ws + alloc((size_t)NG * NH * 4));
  float*  Baff    = (float*)(ws + alloc((size_t)NG * NH * 4));
  ushort* WF1     = (ushort*)(ws + alloc((size_t)2048 * 8 * 2));
  ushort* WF2     = (ushort*)(ws + alloc((size_t)2048 * 8 * 2));
  uchar*  bufA    = (uchar*)(ws + alloc((size_t)NN * NH));       // fp8 gather source, 12.8 MB
  ushort* bufB    = (ushort*)(ws + alloc((size_t)NN * NH * 2));  // bf16 agg output, 25.6 MB
  // sort temps alias bufB (dead until first k_agg write): 12.8 + 1.6 MB <= 25.6 MB
  int2* tmp   = (int2*)bufB;
  int*  ghist = (int*)((char*)bufB + (((size_t)NE * 8 + 255) & ~(size_t)255));
  (void)ws_size; (void)in_sizes; (void)n_in; (void)out_size;

  // prep: counts/gstart via binary search (batch sorted); CSR via counting sort
  k_gstart2<<<1, 128, 0, stream>>>(bat, gstart, counts);
  k_hist<<<NBLK, 256, 0, stream>>>(ei, ghist);
  k_scan1g<<<NSB, 256, 0, stream>>>(ghist, bsums);
  k_scan2<<<1, 512, 0, stream>>>(bsums, NSB);
  k_scan3g<<<NSB, 256, 0, stream>>>(ghist, bsums);
  k_scatter<<<NBLK, 256, 0, stream>>>(ei, ghist, tmp);
  k_fine<<<NB, 256, 0, stream>>>(tmp, ghist, deg, offs, dis, csr);
  k_prepw<<<16, 256, 0, stream>>>(W1, WF1, W2, WF2);

  int gemm_grid = (NN + 63) / 64;   // 1563
  int agg_grid  = (NN + 3) / 4;     // 25000

  // layer 1
  k_gemm<false><<<gemm_grid, 256, 0, stream>>>(x, WF1, dis, bat, nullptr, nullptr, bufA);
  k_agg<<<agg_grid, 256, 0, stream>>>((const uint*)bufA, offs, deg, csr, dis, b1, (u64*)bufB);
  k_stats<<<NG * 16, 256, 0, stream>>>((const uint*)bufB, gstart, statacc);
  k_fin1<<<NG, 128, 0, stream>>>(statacc, counts, gw1, gb1, ga1, Aaff, Baff);

  // layer 2 (norm fused into GEMM A-fragment load)
  k_gemm<true><<<gemm_grid, 256, 0, stream>>>(bufB, WF2, dis, bat, Aaff, Baff, bufA);
  k_agg<<<agg_grid, 256, 0, stream>>>((const uint*)bufA, offs, deg, csr, dis, b2, (u64*)bufB);
  k_stats<<<NG * 16, 256, 0, stream>>>((const uint*)bufB, gstart, statacc);
  k_fin2head<<<NG, 128, 0, stream>>>(statacc, counts, gw2, gb2, ga2, Wc, bc, outp);
}

// Round 10
// 277.425 us; speedup vs baseline: 1.5234x; 1.0649x over previous
//
#include <hip/hip_runtime.h>
#include <cstdint>

#define NN 100000
#define NE 1600000
#define NG 64
#define NH 128
#define NC 10
#define EPSV 1e-5f

#define NB 782                       // (NN+127)>>7 coarse buckets (128 nodes each)
#define NBLK 512                     // histogram/scatter blocks
#define EPB ((NE + NBLK - 1) / NBLK) // 3125 edges per block
#define NSCAN (NB * NBLK)            // 400384, divisible by 1024
#define NSB (NSCAN / 1024)           // 391 scan blocks

typedef __attribute__((ext_vector_type(8))) short bf16x8;
typedef __attribute__((ext_vector_type(4))) float f32x4;
typedef __attribute__((ext_vector_type(2))) float f32x2;
typedef unsigned long long u64;
typedef unsigned char uchar;

__device__ __forceinline__ ushort f2b(float f) {
  uint u = __builtin_bit_cast(uint, f);
  u = (u + 0x7FFFu + ((u >> 16) & 1u)) >> 16;
  return (ushort)u;
}
__device__ __forceinline__ float b2f(ushort h) {
  return __builtin_bit_cast(float, ((uint)h) << 16);
}
__device__ __forceinline__ float lo2f(uint v) { return __builtin_bit_cast(float, v << 16); }
__device__ __forceinline__ float hi2f(uint v) { return __builtin_bit_cast(float, v & 0xFFFF0000u); }

// ---------------- graph prep: counting sort by destination ----------------

__global__ __launch_bounds__(128) void k_gstart2(const int* __restrict__ batch,
                                                 int* __restrict__ gstart, int* __restrict__ counts) {
  __shared__ int lb[NG + 1];
  int t = threadIdx.x;
  if (t <= NG) {                      // first index with batch[i] >= t (batch is sorted)
    int lo = 0, hi = NN;
    while (lo < hi) { int mid = (lo + hi) >> 1; if (batch[mid] < t) lo = mid + 1; else hi = mid; }
    lb[t] = lo;
  }
  __syncthreads();
  if (t < NG) { gstart[t] = lb[t]; counts[t] = lb[t + 1] - lb[t]; }
  if (t == 0) gstart[NG] = NN;
}

__global__ __launch_bounds__(256) void k_hist(const int* __restrict__ ei, int* __restrict__ ghist) {
  __shared__ int h[NB];
  int t = threadIdx.x, blk = blockIdx.x;
  for (int i = t; i < NB; i += 256) h[i] = 0;
  __syncthreads();
  int e0 = blk * EPB, e1 = min(NE, e0 + EPB);
  for (int e = e0 + t; e < e1; e += 256) atomicAdd(&h[ei[NE + e] >> 7], 1);
  __syncthreads();
  for (int i = t; i < NB; i += 256) ghist[i * NBLK + blk] = h[i];
}

__global__ __launch_bounds__(256) void k_scan1g(int* __restrict__ data, int* __restrict__ bsums) {
  __shared__ int sh[256];
  int t = threadIdx.x;
  int base = blockIdx.x * 1024 + t * 4;
  int4 v = *reinterpret_cast<const int4*>(data + base);
  int s = v.x + v.y + v.z + v.w;
  sh[t] = s;
  __syncthreads();
  for (int o = 1; o < 256; o <<= 1) {
    int x = (t >= o) ? sh[t - o] : 0;
    __syncthreads();
    sh[t] += x;
    __syncthreads();
  }
  int ex = sh[t] - s;
  int4 o4;
  o4.x = ex; o4.y = ex + v.x; o4.z = ex + v.x + v.y; o4.w = ex + v.x + v.y + v.z;
  *reinterpret_cast<int4*>(data + base) = o4;
  if (t == 255) bsums[blockIdx.x] = sh[255];
}

__global__ __launch_bounds__(512) void k_scan2(int* bsums, int nb) {
  __shared__ int sh[512];
  int t = threadIdx.x;
  int v = (t < nb) ? bsums[t] : 0;
  sh[t] = v;
  __syncthreads();
  for (int o = 1; o < 512; o <<= 1) {
    int x = (t >= o) ? sh[t - o] : 0;
    __syncthreads();
    sh[t] += x;
    __syncthreads();
  }
  if (t < nb) bsums[t] = sh[t] - v;   // exclusive
}

__global__ __launch_bounds__(256) void k_scan3g(int* __restrict__ data, const int* __restrict__ bsums) {
  int t = threadIdx.x;
  int base = blockIdx.x * 1024 + t * 4;
  int add = bsums[blockIdx.x];
  int4 v = *reinterpret_cast<int4*>(data + base);
  v.x += add; v.y += add; v.z += add; v.w += add;
  *reinterpret_cast<int4*>(data + base) = v;
}

__global__ __launch_bounds__(256) void k_scatter(const int* __restrict__ ei, const int* __restrict__ ghist,
                                                 int2* __restrict__ tmp) {
  __shared__ int cur[NB];
  int t = threadIdx.x, blk = blockIdx.x;
  for (int i = t; i < NB; i += 256) cur[i] = ghist[i * NBLK + blk];
  __syncthreads();
  int e0 = blk * EPB, e1 = min(NE, e0 + EPB);
  for (int e = e0 + t; e < e1; e += 256) {
    int d = ei[NE + e], s = ei[e];
    int p = atomicAdd(&cur[d >> 7], 1);   // LDS atomic (fast, block-local)
    tmp[p] = make_int2(d, s);
  }
}

// fine bucket: per-node deg/offs/dis + CSR (unsorted rows — fast version)
__global__ __launch_bounds__(256) void k_fine(const int2* __restrict__ tmp, const int* __restrict__ ghist,
                                              int* __restrict__ deg, int* __restrict__ offs,
                                              float* __restrict__ dis, int* __restrict__ csr) {
  __shared__ int fh[128], fsc[128], fc[128];
  int b = blockIdx.x, t = threadIdx.x;
  int bs = ghist[b * NBLK];
  int be = (b + 1 < NB) ? ghist[(b + 1) * NBLK] : NE;
  if (t < 128) fh[t] = 0;
  __syncthreads();
  for (int e = bs + t; e < be; e += 256) atomicAdd(&fh[tmp[e].x & 127], 1);
  __syncthreads();
  if (t < 128) fsc[t] = fh[t];
  __syncthreads();
  for (int o = 1; o < 128; o <<= 1) {
    int x = 0;
    if (t < 128 && t >= o) x = fsc[t - o];
    __syncthreads();
    if (t < 128) fsc[t] += x;
    __syncthreads();
  }
  if (t < 128) {
    int ex = fsc[t] - fh[t];
    int node = b * 128 + t;
    fc[t] = bs + ex;
    if (node < NN) {
      deg[node] = fh[t];
      offs[node] = bs + ex;
      dis[node] = rsqrtf((float)(fh[t] + 1));   // +1 self-loop
    }
  }
  __syncthreads();
  for (int e = bs + t; e < be; e += 256) {
    int2 ds = tmp[e];
    int p = atomicAdd(&fc[ds.x & 127], 1);
    csr[p] = ds.y;
  }
}

// ---------------- W pre-pack: fragment-major bf16 B-operand (both layers) ----------------
__global__ __launch_bounds__(256) void k_prepw(const float* __restrict__ W1, ushort* __restrict__ WF1,
                                               const float* __restrict__ W2, ushort* __restrict__ WF2) {
  int tt = blockIdx.x * 256 + threadIdx.x;
  if (tt >= 4096) return;
  const float* W = (tt < 2048) ? W1 : W2;
  ushort* WF = (tt < 2048) ? WF1 : WF2;
  int t = tt & 2047;
  int lane = t & 63, nk = t >> 6;
  int n = nk >> 2, ks = nk & 3;
  int col = n * 16 + (lane & 15);
  int k0 = ks * 32 + (lane >> 4) * 8;
#pragma unroll
  for (int j = 0; j < 8; ++j) WF[(size_t)t * 8 + j] = f2b(W[(k0 + j) * NH + col]);
}

// ---------------- MFMA GEMM: hs_fp8 = (norm?(X) @ W) * dis ----------------
// Wave = 16 rows x 128 cols. Block = 4 waves = 64 rows. Epilogue: fp8 via LDS, coalesced u64 out.
template <bool NORM>
__global__ __launch_bounds__(256) void k_gemm(const void* __restrict__ Xv, const ushort* __restrict__ WF,
                                              const float* __restrict__ dis, const int* __restrict__ batch,
                                              const float* __restrict__ Aaff, const float* __restrict__ Baff,
                                              uchar* __restrict__ out) {
  __shared__ uint sds[4][512];            // per-wave 2KB fp8 staging
  int t = threadIdx.x;
  int w = t >> 6, lane = t & 63;
  int r0 = blockIdx.x * 64 + w * 16;
  int arow = r0 + (lane & 15);
  int khi = lane >> 4;                    // 0..3
  int arowc = (arow < NN) ? arow : (NN - 1);

  f32x4 acc[8];
#pragma unroll
  for (int n = 0; n < 8; ++n) acc[n] = (f32x4){0.f, 0.f, 0.f, 0.f};

  int g = 0;
  if (NORM) g = batch[arowc];
  const bf16x8* WFv = reinterpret_cast<const bf16x8*>(WF);

#pragma unroll
  for (int ks = 0; ks < 4; ++ks) {
    int k0 = ks * 32 + khi * 8;
    bf16x8 a;
    if (!NORM) {
      const float* X = (const float*)Xv;
      float4 x0 = *reinterpret_cast<const float4*>(X + (size_t)arowc * NH + k0);
      float4 x1 = *reinterpret_cast<const float4*>(X + (size_t)arowc * NH + k0 + 4);
      a[0] = (short)f2b(x0.x); a[1] = (short)f2b(x0.y); a[2] = (short)f2b(x0.z); a[3] = (short)f2b(x0.w);
      a[4] = (short)f2b(x1.x); a[5] = (short)f2b(x1.y); a[6] = (short)f2b(x1.z); a[7] = (short)f2b(x1.w);
    } else {
      const ushort* X = (const ushort*)Xv;   // flat bf16 [node][128]
      bf16x8 xr = *reinterpret_cast<const bf16x8*>(X + (size_t)arowc * NH + k0);
      float4 A0 = *reinterpret_cast<const float4*>(Aaff + g * NH + k0);
      float4 A1 = *reinterpret_cast<const float4*>(Aaff + g * NH + k0 + 4);
      float4 B0 = *reinterpret_cast<const float4*>(Baff + g * NH + k0);
      float4 B1 = *reinterpret_cast<const float4*>(Baff + g * NH + k0 + 4);
      a[0] = (short)f2b(fmaf(A0.x, b2f((ushort)xr[0]), B0.x));
      a[1] = (short)f2b(fmaf(A0.y, b2f((ushort)xr[1]), B0.y));
      a[2] = (short)f2b(fmaf(A0.z, b2f((ushort)xr[2]), B0.z));
      a[3] = (short)f2b(fmaf(A0.w, b2f((ushort)xr[3]), B0.w));
      a[4] = (short)f2b(fmaf(A1.x, b2f((ushort)xr[4]), B1.x));
      a[5] = (short)f2b(fmaf(A1.y, b2f((ushort)xr[5]), B1.y));
      a[6] = (short)f2b(fmaf(A1.z, b2f((ushort)xr[6]), B1.z));
      a[7] = (short)f2b(fmaf(A1.w, b2f((ushort)xr[7]), B1.w));
    }
#pragma unroll
    for (int n = 0; n < 8; ++n) {
      bf16x8 b = WFv[(n * 4 + ks) * 64 + lane];
      acc[n] = __builtin_amdgcn_mfma_f32_16x16x32_bf16(a, b, acc[n], 0, 0, 0);
    }
  }

  // epilogue: D (col = n*16 + (lane&15), row = khi*4 + reg) -> fp8 bytes in LDS
  int colb = lane & 15;
  uchar* sb = (uchar*)sds[w];
#pragma unroll
  for (int reg = 0; reg < 4; ++reg) {
    int row = khi * 4 + reg;
    int grow = r0 + row;
    float d = (grow < NN) ? dis[grow] : 0.f;
#pragma unroll
    for (int n = 0; n < 8; n += 2) {
      int p2 = __builtin_amdgcn_cvt_pk_fp8_f32(acc[n][reg] * d, acc[n + 1][reg] * d, 0, false);
      sb[row * 128 + n * 16 + colb] = (uchar)(p2 & 0xFF);
      sb[row * 128 + (n + 1) * 16 + colb] = (uchar)((p2 >> 8) & 0xFF);
    }
  }
  __syncthreads();
  // coalesced write-out: 16 rows x 128B contiguous per wave
  const u64* ss = (const u64*)sds[w];
  u64* gout = (u64*)(out + (size_t)r0 * 128);
#pragma unroll
  for (int it = 0; it < 4; ++it) {
    int idx = it * 64 + lane;
    int row = idx >> 4;
    if (r0 + row < NN) __builtin_nontemporal_store(ss[idx], &gout[idx]);
  }
}

// ---------------- aggregation: t = relu(dis[i]*(hs[i]+sum_src hs[src]) + b) ----------------
// fp8 source (128 B/row). 1 node/wave; 4 groups of 16 lanes each handle a DIFFERENT edge;
// lane loads u64 (8 fp8 feats). 16 edges in flight per unrolled iteration.
// Cross-group combine: shfl_xor(16) + shfl_xor(32) on 8 accumulators, once per node.
__global__ __launch_bounds__(256) void k_agg(const u64* __restrict__ hf8, const int* __restrict__ offs,
                                             const int* __restrict__ deg, const int* __restrict__ csr,
                                             const float* __restrict__ dis, const float* __restrict__ bias,
                                             u64* __restrict__ outb) {
  int w = threadIdx.x >> 6, lane = threadIdx.x & 63;
  int grp = lane >> 4, sub = lane & 15;
  int node = blockIdx.x * 4 + w;
  if (node >= NN) return;
  float a0 = 0.f, a1 = 0.f, a2 = 0.f, a3 = 0.f, a4 = 0.f, a5 = 0.f, a6 = 0.f, a7 = 0.f;
#define ACCUM(V)                                                          \
  {                                                                       \
    uint lo_ = (uint)(V), hi_ = (uint)((V) >> 32);                        \
    f32x2 p0_ = __builtin_amdgcn_cvt_pk_f32_fp8((int)lo_, false);         \
    f32x2 p1_ = __builtin_amdgcn_cvt_pk_f32_fp8((int)lo_, true);          \
    f32x2 p2_ = __builtin_amdgcn_cvt_pk_f32_fp8((int)hi_, false);         \
    f32x2 p3_ = __builtin_amdgcn_cvt_pk_f32_fp8((int)hi_, true);          \
    a0 += p0_[0]; a1 += p0_[1]; a2 += p1_[0]; a3 += p1_[1];               \
    a4 += p2_[0]; a5 += p2_[1]; a6 += p3_[0]; a7 += p3_[1];               \
  }
  if (grp == 0) {                       // self term counted once
    u64 v = hf8[(size_t)node * 16 + sub];
    ACCUM(v);
  }
  int beg = __builtin_nontemporal_load(offs + node);
  int cnt = __builtin_nontemporal_load(deg + node);
  int i = 0;
  for (; i + 16 <= cnt; i += 16) {      // this group: edges i+grp, +4, +8, +12
    int e0 = __builtin_nontemporal_load(csr + beg + i + grp);
    int e1 = __builtin_nontemporal_load(csr + beg + i + grp + 4);
    int e2 = __builtin_nontemporal_load(csr + beg + i + grp + 8);
    int e3 = __builtin_nontemporal_load(csr + beg + i + grp + 12);
    u64 v0 = hf8[(size_t)e0 * 16 + sub];
    u64 v1 = hf8[(size_t)e1 * 16 + sub];
    u64 v2 = hf8[(size_t)e2 * 16 + sub];
    u64 v3 = hf8[(size_t)e3 * 16 + sub];
    ACCUM(v0); ACCUM(v1); ACCUM(v2); ACCUM(v3);
  }
  for (; i < cnt; i += 4) {             // remainder: predicated per group
    int e = i + grp;
    if (e < cnt) {
      int s = __builtin_nontemporal_load(csr + beg + e);
      u64 v = hf8[(size_t)s * 16 + sub];
      ACCUM(v);
    }
  }
#undef ACCUM
  // combine the 4 groups (lane sub of every group holds feats sub*8..sub*8+7)
  a0 += __shfl_xor(a0, 16); a0 += __shfl_xor(a0, 32);
  a1 += __shfl_xor(a1, 16); a1 += __shfl_xor(a1, 32);
  a2 += __shfl_xor(a2, 16); a2 += __shfl_xor(a2, 32);
  a3 += __shfl_xor(a3, 16); a3 += __shfl_xor(a3, 32);
  a4 += __shfl_xor(a4, 16); a4 += __shfl_xor(a4, 32);
  a5 += __shfl_xor(a5, 16); a5 += __shfl_xor(a5, 32);
  a6 += __shfl_xor(a6, 16); a6 += __shfl_xor(a6, 32);
  a7 += __shfl_xor(a7, 16); a7 += __shfl_xor(a7, 32);
  if (grp == 0) {
    float d = dis[node];
    float4 bA = *reinterpret_cast<const float4*>(bias + sub * 8);
    float4 bB = *reinterpret_cast<const float4*>(bias + sub * 8 + 4);
    float o0 = fmaxf(fmaf(d, a0, bA.x), 0.f);
    float o1 = fmaxf(fmaf(d, a1, bA.y), 0.f);
    float o2 = fmaxf(fmaf(d, a2, bA.z), 0.f);
    float o3 = fmaxf(fmaf(d, a3, bA.w), 0.f);
    float o4 = fmaxf(fmaf(d, a4, bB.x), 0.f);
    float o5 = fmaxf(fmaf(d, a5, bB.y), 0.f);
    float o6 = fmaxf(fmaf(d, a6, bB.z), 0.f);
    float o7 = fmaxf(fmaf(d, a7, bB.w), 0.f);
    u64 p0 = (u64)((uint)f2b(o0) | ((uint)f2b(o1) << 16)) |
             ((u64)((uint)f2b(o2) | ((uint)f2b(o3) << 16)) << 32);
    u64 p1 = (u64)((uint)f2b(o4) | ((uint)f2b(o5) << 16)) |
             ((u64)((uint)f2b(o6) | ((uint)f2b(o7) << 16)) << 32);
    u64* orow = outb + (size_t)node * 32 + sub * 2;
    __builtin_nontemporal_store(p0, orow);
    __builtin_nontemporal_store(p1, orow + 1);
  }
}

// ---------------- GraphNorm stats: per-(g,f) sum & sumsq partials (no atomics) ----------------
__global__ __launch_bounds__(256) void k_stats(const uint* __restrict__ t2, const int* __restrict__ gstart,
                                               float* __restrict__ acc) {
  int g = blockIdx.x >> 4, s = blockIdx.x & 15;
  int beg = gstart[g], end = gstart[g + 1];
  int f2 = threadIdx.x & 63, q = threadIdx.x >> 6;   // 4 row-groups
  float sx = 0.f, qx = 0.f, sy = 0.f, qy = 0.f;
  for (int n = beg + s * 4 + q; n < end; n += 64) {
    uint v = t2[(size_t)n * 64 + f2];
    float a = lo2f(v), b = hi2f(v);
    sx += a; qx = fmaf(a, a, qx);
    sy += b; qy = fmaf(b, b, qy);
  }
  __shared__ float sh[4][256];
  sh[0][threadIdx.x] = sx; sh[1][threadIdx.x] = qx;
  sh[2][threadIdx.x] = sy; sh[3][threadIdx.x] = qy;
  __syncthreads();
  if (q == 0) {
#pragma unroll
    for (int qq = 1; qq < 4; ++qq) {
      int idx = (qq << 6) | f2;
      sx += sh[0][idx]; qx += sh[1][idx];
      sy += sh[2][idx]; qy += sh[3][idx];
    }
    int f = f2 * 2;
    float* dst = acc + (size_t)(s * NG + g) * 2 * NH;
    dst[f] = sx; dst[f + 1] = sy;
    dst[NH + f] = qx; dst[NH + f + 1] = qy;
  }
}

__global__ __launch_bounds__(128) void k_fin1(const float* __restrict__ acc, const int* __restrict__ counts,
                                              const float* __restrict__ gw, const float* __restrict__ gb,
                                              const float* __restrict__ ga,
                                              float* __restrict__ Aaff, float* __restrict__ Baff) {
  int g = blockIdx.x, f = threadIdx.x;
  float sum = 0.f, sq = 0.f;
#pragma unroll 4
  for (int s = 0; s < 16; ++s) {
    const float* d = acc + (size_t)(s * NG + g) * 2 * NH;
    sum += d[f];
    sq += d[NH + f];
  }
  float cnt = fmaxf((float)counts[g], 1.f);
  float m = sum / cnt;
  float ex2 = sq / cnt;
  float a = ga[f];
  float var = ex2 - 2.f * a * m * m + a * a * m * m;
  float rstd = rsqrtf(var + EPSV);
  float A = gw[f] * rstd;
  Aaff[g * NH + f] = A;
  Baff[g * NH + f] = gb[f] - A * a * m;
}

// fused layer-2 finalize + classifier head + softmax
__global__ __launch_bounds__(128) void k_fin2head(const float* __restrict__ acc, const int* __restrict__ counts,
                                                  const float* __restrict__ gw, const float* __restrict__ gb,
                                                  const float* __restrict__ ga, const float* __restrict__ Wc,
                                                  const float* __restrict__ bc, float* __restrict__ outp) {
  __shared__ float pool[NH];
  __shared__ float lg[NC];
  int g = blockIdx.x, f = threadIdx.x;
  float sum = 0.f, sq = 0.f;
#pragma unroll 4
  for (int s = 0; s < 16; ++s) {
    const float* d = acc + (size_t)(s * NG + g) * 2 * NH;
    sum += d[f];
    sq += d[NH + f];
  }
  float cnt = fmaxf((float)counts[g], 1.f);
  float m = sum / cnt;
  float ex2 = sq / cnt;
  float a = ga[f];
  float var = ex2 - 2.f * a * m * m + a * a * m * m;
  float rstd = rsqrtf(var + EPSV);
  pool[f] = gw[f] * rstd * (m - a * m) + gb[f];
  __syncthreads();
  if (f < NC) {
    float s = bc[f];
    for (int h = 0; h < NH; ++h) s = fmaf(pool[h], Wc[h * NC + f], s);
    lg[f] = s;
  }
  __syncthreads();
  if (f == 0) {
    float mx = lg[0];
    for (int c = 1; c < NC; ++c) mx = fmaxf(mx, lg[c]);
    float ex[NC];
    float ssum = 0.f;
    for (int c = 0; c < NC; ++c) { ex[c] = __expf(lg[c] - mx); ssum += ex[c]; }
    float inv = 1.f / ssum;
    for (int c = 0; c < NC; ++c) outp[g * NC + c] = ex[c] * inv;
  }
}

// ---------------- launch ----------------
extern "C" void kernel_launch(void* const* d_in, const int* in_sizes, int n_in,
                              void* d_out, int out_size, void* d_ws, size_t ws_size,
                              hipStream_t stream) {
  const float* x   = (const float*)d_in[0];
  const int*   ei  = (const int*)d_in[1];
  const int*   bat = (const int*)d_in[2];
  const float* W1  = (const float*)d_in[3];
  const float* b1  = (const float*)d_in[4];
  const float* gw1 = (const float*)d_in[5];
  const float* gb1 = (const float*)d_in[6];
  const float* ga1 = (const float*)d_in[7];
  const float* W2  = (const float*)d_in[8];
  const float* b2  = (const float*)d_in[9];
  const float* gw2 = (const float*)d_in[10];
  const float* gb2 = (const float*)d_in[11];
  const float* ga2 = (const float*)d_in[12];
  const float* Wc  = (const float*)d_in[13];
  const float* bc  = (const float*)d_in[14];
  float* outp = (float*)d_out;

  char* ws = (char*)d_ws;
  size_t off = 0;
  auto alloc = [&](size_t b) { size_t p = off; off += (b + 255) & ~(size_t)255; return p; };
  int*    deg     = (int*)(ws + alloc((size_t)NN * 4));
  float*  dis     = (float*)(ws + alloc((size_t)NN * 4));
  int*    counts  = (int*)(ws + alloc(NG * 4));
  int*    gstart  = (int*)(ws + alloc((NG + 1) * 4));
  int*    offs    = (int*)(ws + alloc((size_t)NN * 4));
  int*    bsums   = (int*)(ws + alloc(512 * 4));
  int*    csr     = (int*)(ws + alloc((size_t)NE * 4));
  float*  statacc = (float*)(ws + alloc((size_t)16 * NG * 2 * NH * 4));   // 1 MB partials
  float*  Aaff    = (float*)(ws + alloc((size_t)NG * NH * 4));
  float*  Baff    = (float*)(ws + alloc((size_t)NG * NH * 4));
  ushort* WF1     = (ushort*)(ws + alloc((size_t)2048 * 8 * 2));
  ushort* WF2     = (ushort*)(ws + alloc((size_t)2048 * 8 * 2));
  uchar*  bufA    = (uchar*)(ws + alloc((size_t)NN * NH));       // fp8 gather source, 12.8 MB
  ushort* bufB    = (ushort*)(ws + alloc((size_t)NN * NH * 2));  // bf16 agg output, 25.6 MB
  // sort temps alias bufB (dead until first k_agg write): 12.8 + 1.6 MB <= 25.6 MB
  int2* tmp   = (int2*)bufB;
  int*  ghist = (int*)((char*)bufB + (((size_t)NE * 8 + 255) & ~(size_t)255));
  (void)ws_size; (void)in_sizes; (void)n_in; (void)out_size;

  // prep: counts/gstart via binary search (batch sorted); CSR via counting sort
  k_gstart2<<<1, 128, 0, stream>>>(bat, gstart, counts);
  k_hist<<<NBLK, 256, 0, stream>>>(ei, ghist);
  k_scan1g<<<NSB, 256, 0, stream>>>(ghist, bsums);
  k_scan2<<<1, 512, 0, stream>>>(bsums, NSB);
  k_scan3g<<<NSB, 256, 0, stream>>>(ghist, bsums);
  k_scatter<<<NBLK, 256, 0, stream>>>(ei, ghist, tmp);
  k_fine<<<NB, 256, 0, stream>>>(tmp, ghist, deg, offs, dis, csr);
  k_prepw<<<16, 256, 0, stream>>>(W1, WF1, W2, WF2);

  int gemm_grid = (NN + 63) / 64;   // 1563
  int agg_grid  = (NN + 3) / 4;     // 25000

  // layer 1
  k_gemm<false><<<gemm_grid, 256, 0, stream>>>(x, WF1, dis, bat, nullptr, nullptr, bufA);
  k_agg<<<agg_grid, 256, 0, stream>>>((const u64*)bufA, offs, deg, csr, dis, b1, (u64*)bufB);
  k_stats<<<NG * 16, 256, 0, stream>>>((const uint*)bufB, gstart, statacc);
  k_fin1<<<NG, 128, 0, stream>>>(statacc, counts, gw1, gb1, ga1, Aaff, Baff);

  // layer 2 (norm fused into GEMM A-fragment load)
  k_gemm<true><<<gemm_grid, 256, 0, stream>>>(bufB, WF2, dis, bat, Aaff, Baff, bufA);
  k_agg<<<agg_grid, 256, 0, stream>>>((const u64*)bufA, offs, deg, csr, dis, b2, (u64*)bufB);
  k_stats<<<NG * 16, 256, 0, stream>>>((const uint*)bufB, gstart, statacc);
  k_fin2head<<<NG, 128, 0, stream>>>(statacc, counts, gw2, gb2, ga2, Wc, bc, outp);
}

// Round 11
// 261.991 us; speedup vs baseline: 1.6131x; 1.0589x over previous
//
#include <hip/hip_runtime.h>
#include <cstdint>

#define NN 100000
#define NE 1600000
#define NG 64
#define NH 128
#define NC 10
#define EPSV 1e-5f

#define NB 782                       // (NN+127)>>7 coarse buckets (128 nodes each)
#define NBLK 512                     // histogram/scatter blocks
#define EPB ((NE + NBLK - 1) / NBLK) // 3125 edges per block
#define NSCAN (NB * NBLK)            // 400384, divisible by 1024
#define NSB (NSCAN / 1024)           // 391 scan blocks

typedef __attribute__((ext_vector_type(8))) short bf16x8;
typedef __attribute__((ext_vector_type(4))) float f32x4;
typedef __attribute__((ext_vector_type(2))) float f32x2;
typedef unsigned long long u64;
typedef unsigned char uchar;

__device__ __forceinline__ ushort f2b(float f) {
  uint u = __builtin_bit_cast(uint, f);
  u = (u + 0x7FFFu + ((u >> 16) & 1u)) >> 16;
  return (ushort)u;
}
__device__ __forceinline__ float b2f(ushort h) {
  return __builtin_bit_cast(float, ((uint)h) << 16);
}

// ---------------- graph prep: counting sort by destination ----------------

__global__ __launch_bounds__(128) void k_gstart2(const int* __restrict__ batch,
                                                 int* __restrict__ gstart, int* __restrict__ counts) {
  __shared__ int lb[NG + 1];
  int t = threadIdx.x;
  if (t <= NG) {                      // first index with batch[i] >= t (batch is sorted)
    int lo = 0, hi = NN;
    while (lo < hi) { int mid = (lo + hi) >> 1; if (batch[mid] < t) lo = mid + 1; else hi = mid; }
    lb[t] = lo;
  }
  __syncthreads();
  if (t < NG) { gstart[t] = lb[t]; counts[t] = lb[t + 1] - lb[t]; }
  if (t == 0) gstart[NG] = NN;
}

__global__ __launch_bounds__(256) void k_hist(const int* __restrict__ ei, int* __restrict__ ghist) {
  __shared__ int h[NB];
  int t = threadIdx.x, blk = blockIdx.x;
  for (int i = t; i < NB; i += 256) h[i] = 0;
  __syncthreads();
  int e0 = blk * EPB, e1 = min(NE, e0 + EPB);
  for (int e = e0 + t; e < e1; e += 256) atomicAdd(&h[ei[NE + e] >> 7], 1);
  __syncthreads();
  for (int i = t; i < NB; i += 256) ghist[i * NBLK + blk] = h[i];
}

__global__ __launch_bounds__(256) void k_scan1g(int* __restrict__ data, int* __restrict__ bsums) {
  __shared__ int sh[256];
  int t = threadIdx.x;
  int base = blockIdx.x * 1024 + t * 4;
  int4 v = *reinterpret_cast<const int4*>(data + base);
  int s = v.x + v.y + v.z + v.w;
  sh[t] = s;
  __syncthreads();
  for (int o = 1; o < 256; o <<= 1) {
    int x = (t >= o) ? sh[t - o] : 0;
    __syncthreads();
    sh[t] += x;
    __syncthreads();
  }
  int ex = sh[t] - s;
  int4 o4;
  o4.x = ex; o4.y = ex + v.x; o4.z = ex + v.x + v.y; o4.w = ex + v.x + v.y + v.z;
  *reinterpret_cast<int4*>(data + base) = o4;
  if (t == 255) bsums[blockIdx.x] = sh[255];
}

__global__ __launch_bounds__(512) void k_scan2(int* bsums, int nb) {
  __shared__ int sh[512];
  int t = threadIdx.x;
  int v = (t < nb) ? bsums[t] : 0;
  sh[t] = v;
  __syncthreads();
  for (int o = 1; o < 512; o <<= 1) {
    int x = (t >= o) ? sh[t - o] : 0;
    __syncthreads();
    sh[t] += x;
    __syncthreads();
  }
  if (t < nb) bsums[t] = sh[t] - v;   // exclusive
}

__global__ __launch_bounds__(256) void k_scan3g(int* __restrict__ data, const int* __restrict__ bsums) {
  int t = threadIdx.x;
  int base = blockIdx.x * 1024 + t * 4;
  int add = bsums[blockIdx.x];
  int4 v = *reinterpret_cast<int4*>(data + base);
  v.x += add; v.y += add; v.z += add; v.w += add;
  *reinterpret_cast<int4*>(data + base) = v;
}

// scatter: pack (dlocal, src) into one int: (d&127)<<17 | s  (s < 2^17)
__global__ __launch_bounds__(256) void k_scatter(const int* __restrict__ ei, const int* __restrict__ ghist,
                                                 int* __restrict__ tmp) {
  __shared__ int cur[NB];
  int t = threadIdx.x, blk = blockIdx.x;
  for (int i = t; i < NB; i += 256) cur[i] = ghist[i * NBLK + blk];
  __syncthreads();
  int e0 = blk * EPB, e1 = min(NE, e0 + EPB);
  for (int e = e0 + t; e < e1; e += 256) {
    int d = ei[NE + e], s = ei[e];
    int p = atomicAdd(&cur[d >> 7], 1);   // LDS atomic (fast, block-local)
    tmp[p] = ((d & 127) << 17) | s;
  }
}

// fine bucket: per-node deg/offs/dis + CSR
__global__ __launch_bounds__(256) void k_fine(const int* __restrict__ tmp, const int* __restrict__ ghist,
                                              int* __restrict__ deg, int* __restrict__ offs,
                                              float* __restrict__ dis, int* __restrict__ csr) {
  __shared__ int fh[128], fsc[128], fc[128];
  int b = blockIdx.x, t = threadIdx.x;
  int bs = ghist[b * NBLK];
  int be = (b + 1 < NB) ? ghist[(b + 1) * NBLK] : NE;
  if (t < 128) fh[t] = 0;
  __syncthreads();
  for (int e = bs + t; e < be; e += 256) atomicAdd(&fh[tmp[e] >> 17], 1);
  __syncthreads();
  if (t < 128) fsc[t] = fh[t];
  __syncthreads();
  for (int o = 1; o < 128; o <<= 1) {
    int x = 0;
    if (t < 128 && t >= o) x = fsc[t - o];
    __syncthreads();
    if (t < 128) fsc[t] += x;
    __syncthreads();
  }
  if (t < 128) {
    int ex = fsc[t] - fh[t];
    int node = b * 128 + t;
    fc[t] = bs + ex;
    if (node < NN) {
      deg[node] = fh[t];
      offs[node] = bs + ex;
      dis[node] = rsqrtf((float)(fh[t] + 1));   // +1 self-loop
    }
  }
  __syncthreads();
  for (int e = bs + t; e < be; e += 256) {
    int v = tmp[e];
    int p = atomicAdd(&fc[v >> 17], 1);
    csr[p] = v & 0x1FFFF;
  }
}

// ---------------- W pre-pack: fragment-major bf16 B-operand (both layers) ----------------
__global__ __launch_bounds__(256) void k_prepw(const float* __restrict__ W1, ushort* __restrict__ WF1,
                                               const float* __restrict__ W2, ushort* __restrict__ WF2) {
  int tt = blockIdx.x * 256 + threadIdx.x;
  if (tt >= 4096) return;
  const float* W = (tt < 2048) ? W1 : W2;
  ushort* WF = (tt < 2048) ? WF1 : WF2;
  int t = tt & 2047;
  int lane = t & 63, nk = t >> 6;
  int n = nk >> 2, ks = nk & 3;
  int col = n * 16 + (lane & 15);
  int k0 = ks * 32 + (lane >> 4) * 8;
#pragma unroll
  for (int j = 0; j < 8; ++j) WF[(size_t)t * 8 + j] = f2b(W[(k0 + j) * NH + col]);
}

// ---------------- MFMA GEMM: hs_fp8 = (norm?(X) @ W) * dis ----------------
// Wave = 16 rows x 128 cols. Block = 4 waves = 64 rows. NORM path reads fp8 A-input.
template <bool NORM>
__global__ __launch_bounds__(256) void k_gemm(const void* __restrict__ Xv, const ushort* __restrict__ WF,
                                              const float* __restrict__ dis, const int* __restrict__ batch,
                                              const float* __restrict__ Aaff, const float* __restrict__ Baff,
                                              uchar* __restrict__ out) {
  __shared__ uint sds[4][512];            // per-wave 2KB fp8 staging
  int t = threadIdx.x;
  int w = t >> 6, lane = t & 63;
  int r0 = blockIdx.x * 64 + w * 16;
  int arow = r0 + (lane & 15);
  int khi = lane >> 4;                    // 0..3
  int arowc = (arow < NN) ? arow : (NN - 1);

  f32x4 acc[8];
#pragma unroll
  for (int n = 0; n < 8; ++n) acc[n] = (f32x4){0.f, 0.f, 0.f, 0.f};

  int g = 0;
  if (NORM) g = batch[arowc];
  const bf16x8* WFv = reinterpret_cast<const bf16x8*>(WF);

#pragma unroll
  for (int ks = 0; ks < 4; ++ks) {
    int k0 = ks * 32 + khi * 8;
    bf16x8 a;
    if (!NORM) {
      const float* X = (const float*)Xv;
      float4 x0 = *reinterpret_cast<const float4*>(X + (size_t)arowc * NH + k0);
      float4 x1 = *reinterpret_cast<const float4*>(X + (size_t)arowc * NH + k0 + 4);
      a[0] = (short)f2b(x0.x); a[1] = (short)f2b(x0.y); a[2] = (short)f2b(x0.z); a[3] = (short)f2b(x0.w);
      a[4] = (short)f2b(x1.x); a[5] = (short)f2b(x1.y); a[6] = (short)f2b(x1.z); a[7] = (short)f2b(x1.w);
    } else {
      const uchar* X8 = (const uchar*)Xv;  // fp8 [node][128]
      u64 v = *reinterpret_cast<const u64*>(X8 + (size_t)arowc * NH + k0);
      uint lo = (uint)v, hi = (uint)(v >> 32);
      f32x2 x01 = __builtin_amdgcn_cvt_pk_f32_fp8((int)lo, false);
      f32x2 x23 = __builtin_amdgcn_cvt_pk_f32_fp8((int)lo, true);
      f32x2 x45 = __builtin_amdgcn_cvt_pk_f32_fp8((int)hi, false);
      f32x2 x67 = __builtin_amdgcn_cvt_pk_f32_fp8((int)hi, true);
      float4 A0 = *reinterpret_cast<const float4*>(Aaff + g * NH + k0);
      float4 A1 = *reinterpret_cast<const float4*>(Aaff + g * NH + k0 + 4);
      float4 B0 = *reinterpret_cast<const float4*>(Baff + g * NH + k0);
      float4 B1 = *reinterpret_cast<const float4*>(Baff + g * NH + k0 + 4);
      a[0] = (short)f2b(fmaf(A0.x, x01[0], B0.x));
      a[1] = (short)f2b(fmaf(A0.y, x01[1], B0.y));
      a[2] = (short)f2b(fmaf(A0.z, x23[0], B0.z));
      a[3] = (short)f2b(fmaf(A0.w, x23[1], B0.w));
      a[4] = (short)f2b(fmaf(A1.x, x45[0], B1.x));
      a[5] = (short)f2b(fmaf(A1.y, x45[1], B1.y));
      a[6] = (short)f2b(fmaf(A1.z, x67[0], B1.z));
      a[7] = (short)f2b(fmaf(A1.w, x67[1], B1.w));
    }
#pragma unroll
    for (int n = 0; n < 8; ++n) {
      bf16x8 b = WFv[(n * 4 + ks) * 64 + lane];
      acc[n] = __builtin_amdgcn_mfma_f32_16x16x32_bf16(a, b, acc[n], 0, 0, 0);
    }
  }

  // epilogue: D (col = n*16 + (lane&15), row = khi*4 + reg) -> fp8 bytes in LDS
  int colb = lane & 15;
  uchar* sb = (uchar*)sds[w];
#pragma unroll
  for (int reg = 0; reg < 4; ++reg) {
    int row = khi * 4 + reg;
    int grow = r0 + row;
    float d = (grow < NN) ? dis[grow] : 0.f;
#pragma unroll
    for (int n = 0; n < 8; n += 2) {
      int p2 = __builtin_amdgcn_cvt_pk_fp8_f32(acc[n][reg] * d, acc[n + 1][reg] * d, 0, false);
      sb[row * 128 + n * 16 + colb] = (uchar)(p2 & 0xFF);
      sb[row * 128 + (n + 1) * 16 + colb] = (uchar)((p2 >> 8) & 0xFF);
    }
  }
  __syncthreads();
  // coalesced write-out: 16 rows x 128B contiguous per wave
  const u64* ss = (const u64*)sds[w];
  u64* gout = (u64*)(out + (size_t)r0 * 128);
#pragma unroll
  for (int it = 0; it < 4; ++it) {
    int idx = it * 64 + lane;
    int row = idx >> 4;
    if (r0 + row < NN) __builtin_nontemporal_store(ss[idx], &gout[idx]);
  }
}

// ---------------- aggregation: t = relu(dis[i]*(hs[i]+sum_src hs[src]) + b), fp8 in/out ----------------
// 1 node/wave; 4 groups of 16 lanes each handle a different edge; lane loads u64 (8 fp8).
// Packed f32x2 accumulators -> v_pk_add_f32. Cross-group combine via shfl_xor(16,32).
__global__ __launch_bounds__(256) void k_agg(const u64* __restrict__ hf8, const int* __restrict__ offs,
                                             const int* __restrict__ deg, const int* __restrict__ csr,
                                             const float* __restrict__ dis, const float* __restrict__ bias,
                                             u64* __restrict__ outb) {
  int w = threadIdx.x >> 6, lane = threadIdx.x & 63;
  int grp = lane >> 4, sub = lane & 15;
  int node = blockIdx.x * 4 + w;
  if (node >= NN) return;
  f32x2 a01 = (f32x2){0.f, 0.f}, a23 = (f32x2){0.f, 0.f};
  f32x2 a45 = (f32x2){0.f, 0.f}, a67 = (f32x2){0.f, 0.f};
#define ACCUM(V)                                                          \
  {                                                                       \
    uint lo_ = (uint)(V), hi_ = (uint)((V) >> 32);                        \
    a01 += __builtin_amdgcn_cvt_pk_f32_fp8((int)lo_, false);              \
    a23 += __builtin_amdgcn_cvt_pk_f32_fp8((int)lo_, true);               \
    a45 += __builtin_amdgcn_cvt_pk_f32_fp8((int)hi_, false);              \
    a67 += __builtin_amdgcn_cvt_pk_f32_fp8((int)hi_, true);               \
  }
  if (grp == 0) {                       // self term counted once
    u64 v = hf8[(size_t)node * 16 + sub];
    ACCUM(v);
  }
  int beg = __builtin_nontemporal_load(offs + node);
  int cnt = __builtin_nontemporal_load(deg + node);
  int i = 0;
  for (; i + 16 <= cnt; i += 16) {      // this group: edges i+grp, +4, +8, +12
    int e0 = __builtin_nontemporal_load(csr + beg + i + grp);
    int e1 = __builtin_nontemporal_load(csr + beg + i + grp + 4);
    int e2 = __builtin_nontemporal_load(csr + beg + i + grp + 8);
    int e3 = __builtin_nontemporal_load(csr + beg + i + grp + 12);
    u64 v0 = hf8[(size_t)e0 * 16 + sub];
    u64 v1 = hf8[(size_t)e1 * 16 + sub];
    u64 v2 = hf8[(size_t)e2 * 16 + sub];
    u64 v3 = hf8[(size_t)e3 * 16 + sub];
    ACCUM(v0); ACCUM(v1); ACCUM(v2); ACCUM(v3);
  }
  for (; i < cnt; i += 4) {             // remainder: predicated per group
    int e = i + grp;
    if (e < cnt) {
      int s = __builtin_nontemporal_load(csr + beg + e);
      u64 v = hf8[(size_t)s * 16 + sub];
      ACCUM(v);
    }
  }
#undef ACCUM
  float a0 = a01[0], a1 = a01[1], a2 = a23[0], a3 = a23[1];
  float a4 = a45[0], a5 = a45[1], a6 = a67[0], a7 = a67[1];
  a0 += __shfl_xor(a0, 16); a0 += __shfl_xor(a0, 32);
  a1 += __shfl_xor(a1, 16); a1 += __shfl_xor(a1, 32);
  a2 += __shfl_xor(a2, 16); a2 += __shfl_xor(a2, 32);
  a3 += __shfl_xor(a3, 16); a3 += __shfl_xor(a3, 32);
  a4 += __shfl_xor(a4, 16); a4 += __shfl_xor(a4, 32);
  a5 += __shfl_xor(a5, 16); a5 += __shfl_xor(a5, 32);
  a6 += __shfl_xor(a6, 16); a6 += __shfl_xor(a6, 32);
  a7 += __shfl_xor(a7, 16); a7 += __shfl_xor(a7, 32);
  if (grp == 0) {
    float d = dis[node];
    float4 bA = *reinterpret_cast<const float4*>(bias + sub * 8);
    float4 bB = *reinterpret_cast<const float4*>(bias + sub * 8 + 4);
    float o0 = fmaxf(fmaf(d, a0, bA.x), 0.f);
    float o1 = fmaxf(fmaf(d, a1, bA.y), 0.f);
    float o2 = fmaxf(fmaf(d, a2, bA.z), 0.f);
    float o3 = fmaxf(fmaf(d, a3, bA.w), 0.f);
    float o4 = fmaxf(fmaf(d, a4, bB.x), 0.f);
    float o5 = fmaxf(fmaf(d, a5, bB.y), 0.f);
    float o6 = fmaxf(fmaf(d, a6, bB.z), 0.f);
    float o7 = fmaxf(fmaf(d, a7, bB.w), 0.f);
    uint b01 = (uint)__builtin_amdgcn_cvt_pk_fp8_f32(o0, o1, 0, false) & 0xFFFFu;
    uint b23 = (uint)__builtin_amdgcn_cvt_pk_fp8_f32(o2, o3, 0, false) & 0xFFFFu;
    uint b45 = (uint)__builtin_amdgcn_cvt_pk_fp8_f32(o4, o5, 0, false) & 0xFFFFu;
    uint b67 = (uint)__builtin_amdgcn_cvt_pk_fp8_f32(o6, o7, 0, false) & 0xFFFFu;
    u64 pk = (u64)(b01 | (b23 << 16)) | ((u64)(b45 | (b67 << 16)) << 32);
    __builtin_nontemporal_store(pk, &outb[(size_t)node * 16 + sub]);
  }
}

// ---------------- GraphNorm stats: per-(g,f) sum & sumsq partials, fp8 input ----------------
__global__ __launch_bounds__(256) void k_stats(const uint* __restrict__ t8, const int* __restrict__ gstart,
                                               float* __restrict__ acc) {
  int g = blockIdx.x >> 4, s = blockIdx.x & 15;
  int beg = gstart[g], end = gstart[g + 1];
  int j = threadIdx.x & 31, q = threadIdx.x >> 5;   // 32 uints/row (4 feats each), 8 row-groups
  f32x2 s01 = (f32x2){0.f, 0.f}, s23 = (f32x2){0.f, 0.f};
  f32x2 q01 = (f32x2){0.f, 0.f}, q23 = (f32x2){0.f, 0.f};
  for (int n = beg + s * 8 + q; n < end; n += 128) {
    uint v = t8[(size_t)n * 32 + j];
    f32x2 f01 = __builtin_amdgcn_cvt_pk_f32_fp8((int)v, false);
    f32x2 f23 = __builtin_amdgcn_cvt_pk_f32_fp8((int)v, true);
    s01 += f01; s23 += f23;
    q01 += f01 * f01; q23 += f23 * f23;
  }
  __shared__ float shs[256][4];
  __shared__ float shq[256][4];
  int t = threadIdx.x;
  shs[t][0] = s01[0]; shs[t][1] = s01[1]; shs[t][2] = s23[0]; shs[t][3] = s23[1];
  shq[t][0] = q01[0]; shq[t][1] = q01[1]; shq[t][2] = q23[0]; shq[t][3] = q23[1];
  __syncthreads();
  if (q == 0) {
    float sm[4], sq[4];
#pragma unroll
    for (int k = 0; k < 4; ++k) { sm[k] = shs[j][k]; sq[k] = shq[j][k]; }
#pragma unroll
    for (int qq = 1; qq < 8; ++qq) {
      int idx = qq * 32 + j;
#pragma unroll
      for (int k = 0; k < 4; ++k) { sm[k] += shs[idx][k]; sq[k] += shq[idx][k]; }
    }
    int f = j * 4;
    float* dst = acc + (size_t)(s * NG + g) * 2 * NH;
#pragma unroll
    for (int k = 0; k < 4; ++k) { dst[f + k] = sm[k]; dst[NH + f + k] = sq[k]; }
  }
}

__global__ __launch_bounds__(128) void k_fin1(const float* __restrict__ acc, const int* __restrict__ counts,
                                              const float* __restrict__ gw, const float* __restrict__ gb,
                                              const float* __restrict__ ga,
                                              float* __restrict__ Aaff, float* __restrict__ Baff) {
  int g = blockIdx.x, f = threadIdx.x;
  float sum = 0.f, sq = 0.f;
#pragma unroll 4
  for (int s = 0; s < 16; ++s) {
    const float* d = acc + (size_t)(s * NG + g) * 2 * NH;
    sum += d[f];
    sq += d[NH + f];
  }
  float cnt = fmaxf((float)counts[g], 1.f);
  float m = sum / cnt;
  float ex2 = sq / cnt;
  float a = ga[f];
  float var = ex2 - 2.f * a * m * m + a * a * m * m;
  float rstd = rsqrtf(var + EPSV);
  float A = gw[f] * rstd;
  Aaff[g * NH + f] = A;
  Baff[g * NH + f] = gb[f] - A * a * m;
}

// fused layer-2 finalize + classifier head + softmax
__global__ __launch_bounds__(128) void k_fin2head(const float* __restrict__ acc, const int* __restrict__ counts,
                                                  const float* __restrict__ gw, const float* __restrict__ gb,
                                                  const float* __restrict__ ga, const float* __restrict__ Wc,
                                                  const float* __restrict__ bc, float* __restrict__ outp) {
  __shared__ float pool[NH];
  __shared__ float lg[NC];
  int g = blockIdx.x, f = threadIdx.x;
  float sum = 0.f, sq = 0.f;
#pragma unroll 4
  for (int s = 0; s < 16; ++s) {
    const float* d = acc + (size_t)(s * NG + g) * 2 * NH;
    sum += d[f];
    sq += d[NH + f];
  }
  float cnt = fmaxf((float)counts[g], 1.f);
  float m = sum / cnt;
  float ex2 = sq / cnt;
  float a = ga[f];
  float var = ex2 - 2.f * a * m * m + a * a * m * m;
  float rstd = rsqrtf(var + EPSV);
  pool[f] = gw[f] * rstd * (m - a * m) + gb[f];
  __syncthreads();
  if (f < NC) {
    float s = bc[f];
    for (int h = 0; h < NH; ++h) s = fmaf(pool[h], Wc[h * NC + f], s);
    lg[f] = s;
  }
  __syncthreads();
  if (f == 0) {
    float mx = lg[0];
    for (int c = 1; c < NC; ++c) mx = fmaxf(mx, lg[c]);
    float ex[NC];
    float ssum = 0.f;
    for (int c = 0; c < NC; ++c) { ex[c] = __expf(lg[c] - mx); ssum += ex[c]; }
    float inv = 1.f / ssum;
    for (int c = 0; c < NC; ++c) outp[g * NC + c] = ex[c] * inv;
  }
}

// ---------------- launch ----------------
extern "C" void kernel_launch(void* const* d_in, const int* in_sizes, int n_in,
                              void* d_out, int out_size, void* d_ws, size_t ws_size,
                              hipStream_t stream) {
  const float* x   = (const float*)d_in[0];
  const int*   ei  = (const int*)d_in[1];
  const int*   bat = (const int*)d_in[2];
  const float* W1  = (const float*)d_in[3];
  const float* b1  = (const float*)d_in[4];
  const float* gw1 = (const float*)d_in[5];
  const float* gb1 = (const float*)d_in[6];
  const float* ga1 = (const float*)d_in[7];
  const float* W2  = (const float*)d_in[8];
  const float* b2  = (const float*)d_in[9];
  const float* gw2 = (const float*)d_in[10];
  const float* gb2 = (const float*)d_in[11];
  const float* ga2 = (const float*)d_in[12];
  const float* Wc  = (const float*)d_in[13];
  const float* bc  = (const float*)d_in[14];
  float* outp = (float*)d_out;

  char* ws = (char*)d_ws;
  size_t off = 0;
  auto alloc = [&](size_t b) { size_t p = off; off += (b + 255) & ~(size_t)255; return p; };
  int*    deg     = (int*)(ws + alloc((size_t)NN * 4));
  float*  dis     = (float*)(ws + alloc((size_t)NN * 4));
  int*    counts  = (int*)(ws + alloc(NG * 4));
  int*    gstart  = (int*)(ws + alloc((NG + 1) * 4));
  int*    offs    = (int*)(ws + alloc((size_t)NN * 4));
  int*    bsums   = (int*)(ws + alloc(512 * 4));
  int*    csr     = (int*)(ws + alloc((size_t)NE * 4));
  float*  statacc = (float*)(ws + alloc((size_t)16 * NG * 2 * NH * 4));   // 1 MB partials
  float*  Aaff    = (float*)(ws + alloc((size_t)NG * NH * 4));
  float*  Baff    = (float*)(ws + alloc((size_t)NG * NH * 4));
  ushort* WF1     = (ushort*)(ws + alloc((size_t)2048 * 8 * 2));
  ushort* WF2     = (ushort*)(ws + alloc((size_t)2048 * 8 * 2));
  uchar*  bufA    = (uchar*)(ws + alloc((size_t)NN * NH));       // fp8, 12.8 MB
  uchar*  bufB    = (uchar*)(ws + alloc((size_t)NN * NH));       // fp8, 12.8 MB
  // sort temps alias bufB (dead until first k_agg write): 6.4 (packed int) + 1.6 MB <= 12.8 MB
  int* tmp   = (int*)bufB;
  int* ghist = (int*)((char*)bufB + (((size_t)NE * 4 + 255) & ~(size_t)255));
  (void)ws_size; (void)in_sizes; (void)n_in; (void)out_size;

  // prep: counts/gstart via binary search (batch sorted); CSR via counting sort
  k_gstart2<<<1, 128, 0, stream>>>(bat, gstart, counts);
  k_hist<<<NBLK, 256, 0, stream>>>(ei, ghist);
  k_scan1g<<<NSB, 256, 0, stream>>>(ghist, bsums);
  k_scan2<<<1, 512, 0, stream>>>(bsums, NSB);
  k_scan3g<<<NSB, 256, 0, stream>>>(ghist, bsums);
  k_scatter<<<NBLK, 256, 0, stream>>>(ei, ghist, tmp);
  k_fine<<<NB, 256, 0, stream>>>(tmp, ghist, deg, offs, dis, csr);
  k_prepw<<<16, 256, 0, stream>>>(W1, WF1, W2, WF2);

  int gemm_grid = (NN + 63) / 64;   // 1563
  int agg_grid  = (NN + 3) / 4;     // 25000

  // layer 1
  k_gemm<false><<<gemm_grid, 256, 0, stream>>>(x, WF1, dis, bat, nullptr, nullptr, bufA);
  k_agg<<<agg_grid, 256, 0, stream>>>((const u64*)bufA, offs, deg, csr, dis, b1, (u64*)bufB);
  k_stats<<<NG * 16, 256, 0, stream>>>((const uint*)bufB, gstart, statacc);
  k_fin1<<<NG, 128, 0, stream>>>(statacc, counts, gw1, gb1, ga1, Aaff, Baff);

  // layer 2 (norm fused into GEMM A-fragment load, fp8 A-input)
  k_gemm<true><<<gemm_grid, 256, 0, stream>>>(bufB, WF2, dis, bat, Aaff, Baff, bufA);
  k_agg<<<agg_grid, 256, 0, stream>>>((const u64*)bufA, offs, deg, csr, dis, b2, (u64*)bufB);
  k_stats<<<NG * 16, 256, 0, stream>>>((const uint*)bufB, gstart, statacc);
  k_fin2head<<<NG, 128, 0, stream>>>(statacc, counts, gw2, gb2, ga2, Wc, bc, outp);
}

// Round 12
// 241.133 us; speedup vs baseline: 1.7526x; 1.0865x over previous
//
#include <hip/hip_runtime.h>
#include <cstdint>

#define NN 100000
#define NE 1600000
#define NG 64
#define NH 128
#define NC 10
#define EPSV 1e-5f

#define NB 782                       // (NN+127)>>7 coarse buckets (128 nodes each)
#define NBLK 512                     // histogram/scatter blocks
#define EPB ((NE + NBLK - 1) / NBLK) // 3125 edges per block
#define NSCAN (NB * NBLK)            // 400384, divisible by 1024
#define NSB (NSCAN / 1024)           // 391 scan blocks

typedef __attribute__((ext_vector_type(8))) short bf16x8;
typedef __attribute__((ext_vector_type(4))) float f32x4;
typedef __attribute__((ext_vector_type(2))) float f32x2;
typedef unsigned long long u64;
typedef unsigned char uchar;

__device__ __forceinline__ ushort f2b(float f) {
  uint u = __builtin_bit_cast(uint, f);
  u = (u + 0x7FFFu + ((u >> 16) & 1u)) >> 16;
  return (ushort)u;
}
__device__ __forceinline__ float b2f(ushort h) {
  return __builtin_bit_cast(float, ((uint)h) << 16);
}

// ---------------- graph prep: counting sort by destination ----------------
// also zeroes row NN of both feature buffers (gather-pad target)
__global__ __launch_bounds__(128) void k_gstart2(const int* __restrict__ batch,
                                                 int* __restrict__ gstart, int* __restrict__ counts,
                                                 u64* __restrict__ zrowA, u64* __restrict__ zrowB) {
  __shared__ int lb[NG + 1];
  int t = threadIdx.x;
  if (t <= NG) {                      // first index with batch[i] >= t (batch is sorted)
    int lo = 0, hi = NN;
    while (lo < hi) { int mid = (lo + hi) >> 1; if (batch[mid] < t) lo = mid + 1; else hi = mid; }
    lb[t] = lo;
  }
  if (t >= 96 && t < 112) zrowA[t - 96] = 0ull;   // 16 u64 = 128 B row NN
  if (t >= 112) zrowB[t - 112] = 0ull;
  __syncthreads();
  if (t < NG) { gstart[t] = lb[t]; counts[t] = lb[t + 1] - lb[t]; }
  if (t == 0) gstart[NG] = NN;
}

__global__ __launch_bounds__(256) void k_hist(const int* __restrict__ ei, int* __restrict__ ghist) {
  __shared__ int h[NB];
  int t = threadIdx.x, blk = blockIdx.x;
  for (int i = t; i < NB; i += 256) h[i] = 0;
  __syncthreads();
  int e0 = blk * EPB, e1 = min(NE, e0 + EPB);
  for (int e = e0 + t; e < e1; e += 256) atomicAdd(&h[ei[NE + e] >> 7], 1);
  __syncthreads();
  for (int i = t; i < NB; i += 256) ghist[i * NBLK + blk] = h[i];
}

__global__ __launch_bounds__(256) void k_scan1g(int* __restrict__ data, int* __restrict__ bsums) {
  __shared__ int sh[256];
  int t = threadIdx.x;
  int base = blockIdx.x * 1024 + t * 4;
  int4 v = *reinterpret_cast<const int4*>(data + base);
  int s = v.x + v.y + v.z + v.w;
  sh[t] = s;
  __syncthreads();
  for (int o = 1; o < 256; o <<= 1) {
    int x = (t >= o) ? sh[t - o] : 0;
    __syncthreads();
    sh[t] += x;
    __syncthreads();
  }
  int ex = sh[t] - s;
  int4 o4;
  o4.x = ex; o4.y = ex + v.x; o4.z = ex + v.x + v.y; o4.w = ex + v.x + v.y + v.z;
  *reinterpret_cast<int4*>(data + base) = o4;
  if (t == 255) bsums[blockIdx.x] = sh[255];
}

__global__ __launch_bounds__(512) void k_scan2(int* bsums, int nb) {
  __shared__ int sh[512];
  int t = threadIdx.x;
  int v = (t < nb) ? bsums[t] : 0;
  sh[t] = v;
  __syncthreads();
  for (int o = 1; o < 512; o <<= 1) {
    int x = (t >= o) ? sh[t - o] : 0;
    __syncthreads();
    sh[t] += x;
    __syncthreads();
  }
  if (t < nb) bsums[t] = sh[t] - v;   // exclusive
}

__global__ __launch_bounds__(256) void k_scan3g(int* __restrict__ data, const int* __restrict__ bsums) {
  int t = threadIdx.x;
  int base = blockIdx.x * 1024 + t * 4;
  int add = bsums[blockIdx.x];
  int4 v = *reinterpret_cast<int4*>(data + base);
  v.x += add; v.y += add; v.z += add; v.w += add;
  *reinterpret_cast<int4*>(data + base) = v;
}

// scatter: pack (dlocal, src) into one int: (d&127)<<17 | s  (s < 2^17)
__global__ __launch_bounds__(256) void k_scatter(const int* __restrict__ ei, const int* __restrict__ ghist,
                                                 int* __restrict__ tmp) {
  __shared__ int cur[NB];
  int t = threadIdx.x, blk = blockIdx.x;
  for (int i = t; i < NB; i += 256) cur[i] = ghist[i * NBLK + blk];
  __syncthreads();
  int e0 = blk * EPB, e1 = min(NE, e0 + EPB);
  for (int e = e0 + t; e < e1; e += 256) {
    int d = ei[NE + e], s = ei[e];
    int p = atomicAdd(&cur[d >> 7], 1);   // LDS atomic (fast, block-local)
    tmp[p] = ((d & 127) << 17) | s;
  }
}

// fine bucket: per-node deg/offs/dis + CSR
__global__ __launch_bounds__(256) void k_fine(const int* __restrict__ tmp, const int* __restrict__ ghist,
                                              int* __restrict__ deg, int* __restrict__ offs,
                                              float* __restrict__ dis, int* __restrict__ csr) {
  __shared__ int fh[128], fsc[128], fc[128];
  int b = blockIdx.x, t = threadIdx.x;
  int bs = ghist[b * NBLK];
  int be = (b + 1 < NB) ? ghist[(b + 1) * NBLK] : NE;
  if (t < 128) fh[t] = 0;
  __syncthreads();
  for (int e = bs + t; e < be; e += 256) atomicAdd(&fh[tmp[e] >> 17], 1);
  __syncthreads();
  if (t < 128) fsc[t] = fh[t];
  __syncthreads();
  for (int o = 1; o < 128; o <<= 1) {
    int x = 0;
    if (t < 128 && t >= o) x = fsc[t - o];
    __syncthreads();
    if (t < 128) fsc[t] += x;
    __syncthreads();
  }
  if (t < 128) {
    int ex = fsc[t] - fh[t];
    int node = b * 128 + t;
    fc[t] = bs + ex;
    if (node < NN) {
      deg[node] = fh[t];
      offs[node] = bs + ex;
      dis[node] = rsqrtf((float)(fh[t] + 1));   // +1 self-loop
    }
  }
  __syncthreads();
  for (int e = bs + t; e < be; e += 256) {
    int v = tmp[e];
    int p = atomicAdd(&fc[v >> 17], 1);
    csr[p] = v & 0x1FFFF;
  }
}

// ---------------- W pre-pack: fragment-major bf16 B-operand (both layers) ----------------
__global__ __launch_bounds__(256) void k_prepw(const float* __restrict__ W1, ushort* __restrict__ WF1,
                                               const float* __restrict__ W2, ushort* __restrict__ WF2) {
  int tt = blockIdx.x * 256 + threadIdx.x;
  if (tt >= 4096) return;
  const float* W = (tt < 2048) ? W1 : W2;
  ushort* WF = (tt < 2048) ? WF1 : WF2;
  int t = tt & 2047;
  int lane = t & 63, nk = t >> 6;
  int n = nk >> 2, ks = nk & 3;
  int col = n * 16 + (lane & 15);
  int k0 = ks * 32 + (lane >> 4) * 8;
#pragma unroll
  for (int j = 0; j < 8; ++j) WF[(size_t)t * 8 + j] = f2b(W[(k0 + j) * NH + col]);
}

// ---------------- MFMA GEMM: hs_fp8 = (norm?(X) @ W) * dis ----------------
// Wave = 16 rows x 128 cols. Block = 4 waves = 64 rows. NORM path reads fp8 A-input.
template <bool NORM>
__global__ __launch_bounds__(256) void k_gemm(const void* __restrict__ Xv, const ushort* __restrict__ WF,
                                              const float* __restrict__ dis, const int* __restrict__ batch,
                                              const float* __restrict__ Aaff, const float* __restrict__ Baff,
                                              uchar* __restrict__ out) {
  __shared__ uint sds[4][512];            // per-wave 2KB fp8 staging
  int t = threadIdx.x;
  int w = t >> 6, lane = t & 63;
  int r0 = blockIdx.x * 64 + w * 16;
  int arow = r0 + (lane & 15);
  int khi = lane >> 4;                    // 0..3
  int arowc = (arow < NN) ? arow : (NN - 1);

  f32x4 acc[8];
#pragma unroll
  for (int n = 0; n < 8; ++n) acc[n] = (f32x4){0.f, 0.f, 0.f, 0.f};

  int g = 0;
  if (NORM) g = batch[arowc];
  const bf16x8* WFv = reinterpret_cast<const bf16x8*>(WF);

#pragma unroll
  for (int ks = 0; ks < 4; ++ks) {
    int k0 = ks * 32 + khi * 8;
    bf16x8 a;
    if (!NORM) {
      const float* X = (const float*)Xv;
      float4 x0 = *reinterpret_cast<const float4*>(X + (size_t)arowc * NH + k0);
      float4 x1 = *reinterpret_cast<const float4*>(X + (size_t)arowc * NH + k0 + 4);
      a[0] = (short)f2b(x0.x); a[1] = (short)f2b(x0.y); a[2] = (short)f2b(x0.z); a[3] = (short)f2b(x0.w);
      a[4] = (short)f2b(x1.x); a[5] = (short)f2b(x1.y); a[6] = (short)f2b(x1.z); a[7] = (short)f2b(x1.w);
    } else {
      const uchar* X8 = (const uchar*)Xv;  // fp8 [node][128]
      u64 v = *reinterpret_cast<const u64*>(X8 + (size_t)arowc * NH + k0);
      uint lo = (uint)v, hi = (uint)(v >> 32);
      f32x2 x01 = __builtin_amdgcn_cvt_pk_f32_fp8((int)lo, false);
      f32x2 x23 = __builtin_amdgcn_cvt_pk_f32_fp8((int)lo, true);
      f32x2 x45 = __builtin_amdgcn_cvt_pk_f32_fp8((int)hi, false);
      f32x2 x67 = __builtin_amdgcn_cvt_pk_f32_fp8((int)hi, true);
      float4 A0 = *reinterpret_cast<const float4*>(Aaff + g * NH + k0);
      float4 A1 = *reinterpret_cast<const float4*>(Aaff + g * NH + k0 + 4);
      float4 B0 = *reinterpret_cast<const float4*>(Baff + g * NH + k0);
      float4 B1 = *reinterpret_cast<const float4*>(Baff + g * NH + k0 + 4);
      a[0] = (short)f2b(fmaf(A0.x, x01[0], B0.x));
      a[1] = (short)f2b(fmaf(A0.y, x01[1], B0.y));
      a[2] = (short)f2b(fmaf(A0.z, x23[0], B0.z));
      a[3] = (short)f2b(fmaf(A0.w, x23[1], B0.w));
      a[4] = (short)f2b(fmaf(A1.x, x45[0], B1.x));
      a[5] = (short)f2b(fmaf(A1.y, x45[1], B1.y));
      a[6] = (short)f2b(fmaf(A1.z, x67[0], B1.z));
      a[7] = (short)f2b(fmaf(A1.w, x67[1], B1.w));
    }
#pragma unroll
    for (int n = 0; n < 8; ++n) {
      bf16x8 b = WFv[(n * 4 + ks) * 64 + lane];
      acc[n] = __builtin_amdgcn_mfma_f32_16x16x32_bf16(a, b, acc[n], 0, 0, 0);
    }
  }

  // epilogue: D (col = n*16 + (lane&15), row = khi*4 + reg) -> fp8 bytes in LDS
  int colb = lane & 15;
  uchar* sb = (uchar*)sds[w];
#pragma unroll
  for (int reg = 0; reg < 4; ++reg) {
    int row = khi * 4 + reg;
    int grow = r0 + row;
    float d = (grow < NN) ? dis[grow] : 0.f;
#pragma unroll
    for (int n = 0; n < 8; n += 2) {
      int p2 = __builtin_amdgcn_cvt_pk_fp8_f32(acc[n][reg] * d, acc[n + 1][reg] * d, 0, false);
      sb[row * 128 + n * 16 + colb] = (uchar)(p2 & 0xFF);
      sb[row * 128 + (n + 1) * 16 + colb] = (uchar)((p2 >> 8) & 0xFF);
    }
  }
  __syncthreads();
  // coalesced write-out: 16 rows x 128B contiguous per wave
  const u64* ss = (const u64*)sds[w];
  u64* gout = (u64*)(out + (size_t)r0 * 128);
#pragma unroll
  for (int it = 0; it < 4; ++it) {
    int idx = it * 64 + lane;
    int row = idx >> 4;
    if (r0 + row < NN) __builtin_nontemporal_store(ss[idx], &gout[idx]);
  }
}

// ---------------- aggregation: t = relu(dis[i]*(hs[i]+sum_src hs[src]) + b), fp8 in/out ----------------
// 1 node/wave; 4 groups of 16 lanes each handle a different edge; lane loads u64 (8 fp8).
// Tail flattened: ONE parallel chain of 4 predicated quad-loads, invalid lanes read zero row NN.
__global__ __launch_bounds__(256) void k_agg(const u64* __restrict__ hf8, const int* __restrict__ offs,
                                             const int* __restrict__ deg, const int* __restrict__ csr,
                                             const float* __restrict__ dis, const float* __restrict__ bias,
                                             u64* __restrict__ outb) {
  int w = threadIdx.x >> 6, lane = threadIdx.x & 63;
  int grp = lane >> 4, sub = lane & 15;
  int node = blockIdx.x * 4 + w;
  if (node >= NN) return;
  f32x2 a01 = (f32x2){0.f, 0.f}, a23 = (f32x2){0.f, 0.f};
  f32x2 a45 = (f32x2){0.f, 0.f}, a67 = (f32x2){0.f, 0.f};
#define ACCUM(V)                                                          \
  {                                                                       \
    uint lo_ = (uint)(V), hi_ = (uint)((V) >> 32);                        \
    a01 += __builtin_amdgcn_cvt_pk_f32_fp8((int)lo_, false);              \
    a23 += __builtin_amdgcn_cvt_pk_f32_fp8((int)lo_, true);               \
    a45 += __builtin_amdgcn_cvt_pk_f32_fp8((int)hi_, false);              \
    a67 += __builtin_amdgcn_cvt_pk_f32_fp8((int)hi_, true);               \
  }
  if (grp == 0) {                       // self term counted once
    u64 v = hf8[(size_t)node * 16 + sub];
    ACCUM(v);
  }
  int beg = __builtin_nontemporal_load(offs + node);
  int cnt = __builtin_nontemporal_load(deg + node);
  int i = 0;
  for (; i + 16 <= cnt; i += 16) {      // this group: edges i+grp, +4, +8, +12
    int e0 = __builtin_nontemporal_load(csr + beg + i + grp);
    int e1 = __builtin_nontemporal_load(csr + beg + i + grp + 4);
    int e2 = __builtin_nontemporal_load(csr + beg + i + grp + 8);
    int e3 = __builtin_nontemporal_load(csr + beg + i + grp + 12);
    u64 v0 = hf8[(size_t)e0 * 16 + sub];
    u64 v1 = hf8[(size_t)e1 * 16 + sub];
    u64 v2 = hf8[(size_t)e2 * 16 + sub];
    u64 v3 = hf8[(size_t)e3 * 16 + sub];
    ACCUM(v0); ACCUM(v1); ACCUM(v2); ACCUM(v3);
  }
  if (i < cnt) {                        // flattened tail: <=15 edges, ONE chain
    int lim = beg + cnt - 1;
    int p0 = beg + i + grp;
    int p1 = p0 + 4, p2 = p0 + 8, p3 = p0 + 12;
    int c0 = __builtin_nontemporal_load(csr + min(p0, lim));
    int c1 = __builtin_nontemporal_load(csr + min(p1, lim));
    int c2 = __builtin_nontemporal_load(csr + min(p2, lim));
    int c3 = __builtin_nontemporal_load(csr + min(p3, lim));
    int s0 = (p0 <= lim) ? c0 : NN;     // row NN is all zeros
    int s1 = (p1 <= lim) ? c1 : NN;
    int s2 = (p2 <= lim) ? c2 : NN;
    int s3 = (p3 <= lim) ? c3 : NN;
    u64 v0 = hf8[(size_t)s0 * 16 + sub];
    u64 v1 = hf8[(size_t)s1 * 16 + sub];
    u64 v2 = hf8[(size_t)s2 * 16 + sub];
    u64 v3 = hf8[(size_t)s3 * 16 + sub];
    ACCUM(v0); ACCUM(v1); ACCUM(v2); ACCUM(v3);
  }
#undef ACCUM
  float a0 = a01[0], a1 = a01[1], a2 = a23[0], a3 = a23[1];
  float a4 = a45[0], a5 = a45[1], a6 = a67[0], a7 = a67[1];
  a0 += __shfl_xor(a0, 16); a0 += __shfl_xor(a0, 32);
  a1 += __shfl_xor(a1, 16); a1 += __shfl_xor(a1, 32);
  a2 += __shfl_xor(a2, 16); a2 += __shfl_xor(a2, 32);
  a3 += __shfl_xor(a3, 16); a3 += __shfl_xor(a3, 32);
  a4 += __shfl_xor(a4, 16); a4 += __shfl_xor(a4, 32);
  a5 += __shfl_xor(a5, 16); a5 += __shfl_xor(a5, 32);
  a6 += __shfl_xor(a6, 16); a6 += __shfl_xor(a6, 32);
  a7 += __shfl_xor(a7, 16); a7 += __shfl_xor(a7, 32);
  if (grp == 0) {
    float d = dis[node];
    float4 bA = *reinterpret_cast<const float4*>(bias + sub * 8);
    float4 bB = *reinterpret_cast<const float4*>(bias + sub * 8 + 4);
    float o0 = fmaxf(fmaf(d, a0, bA.x), 0.f);
    float o1 = fmaxf(fmaf(d, a1, bA.y), 0.f);
    float o2 = fmaxf(fmaf(d, a2, bA.z), 0.f);
    float o3 = fmaxf(fmaf(d, a3, bA.w), 0.f);
    float o4 = fmaxf(fmaf(d, a4, bB.x), 0.f);
    float o5 = fmaxf(fmaf(d, a5, bB.y), 0.f);
    float o6 = fmaxf(fmaf(d, a6, bB.z), 0.f);
    float o7 = fmaxf(fmaf(d, a7, bB.w), 0.f);
    uint b01 = (uint)__builtin_amdgcn_cvt_pk_fp8_f32(o0, o1, 0, false) & 0xFFFFu;
    uint b23 = (uint)__builtin_amdgcn_cvt_pk_fp8_f32(o2, o3, 0, false) & 0xFFFFu;
    uint b45 = (uint)__builtin_amdgcn_cvt_pk_fp8_f32(o4, o5, 0, false) & 0xFFFFu;
    uint b67 = (uint)__builtin_amdgcn_cvt_pk_fp8_f32(o6, o7, 0, false) & 0xFFFFu;
    u64 pk = (u64)(b01 | (b23 << 16)) | ((u64)(b45 | (b67 << 16)) << 32);
    __builtin_nontemporal_store(pk, &outb[(size_t)node * 16 + sub]);
  }
}

// ---------------- GraphNorm stats: per-(g,f) sum & sumsq partials, fp8 input ----------------
__global__ __launch_bounds__(256) void k_stats(const uint* __restrict__ t8, const int* __restrict__ gstart,
                                               float* __restrict__ acc) {
  int g = blockIdx.x >> 4, s = blockIdx.x & 15;
  int beg = gstart[g], end = gstart[g + 1];
  int j = threadIdx.x & 31, q = threadIdx.x >> 5;   // 32 uints/row (4 feats each), 8 row-groups
  f32x2 s01 = (f32x2){0.f, 0.f}, s23 = (f32x2){0.f, 0.f};
  f32x2 q01 = (f32x2){0.f, 0.f}, q23 = (f32x2){0.f, 0.f};
  for (int n = beg + s * 8 + q; n < end; n += 128) {
    uint v = t8[(size_t)n * 32 + j];
    f32x2 f01 = __builtin_amdgcn_cvt_pk_f32_fp8((int)v, false);
    f32x2 f23 = __builtin_amdgcn_cvt_pk_f32_fp8((int)v, true);
    s01 += f01; s23 += f23;
    q01 += f01 * f01; q23 += f23 * f23;
  }
  __shared__ float shs[256][4];
  __shared__ float shq[256][4];
  int t = threadIdx.x;
  shs[t][0] = s01[0]; shs[t][1] = s01[1]; shs[t][2] = s23[0]; shs[t][3] = s23[1];
  shq[t][0] = q01[0]; shq[t][1] = q01[1]; shq[t][2] = q23[0]; shq[t][3] = q23[1];
  __syncthreads();
  if (q == 0) {
    float sm[4], sq[4];
#pragma unroll
    for (int k = 0; k < 4; ++k) { sm[k] = shs[j][k]; sq[k] = shq[j][k]; }
#pragma unroll
    for (int qq = 1; qq < 8; ++qq) {
      int idx = qq * 32 + j;
#pragma unroll
      for (int k = 0; k < 4; ++k) { sm[k] += shs[idx][k]; sq[k] += shq[idx][k]; }
    }
    int f = j * 4;
    float* dst = acc + (size_t)(s * NG + g) * 2 * NH;
#pragma unroll
    for (int k = 0; k < 4; ++k) { dst[f + k] = sm[k]; dst[NH + f + k] = sq[k]; }
  }
}

__global__ __launch_bounds__(128) void k_fin1(const float* __restrict__ acc, const int* __restrict__ counts,
                                              const float* __restrict__ gw, const float* __restrict__ gb,
                                              const float* __restrict__ ga,
                                              float* __restrict__ Aaff, float* __restrict__ Baff) {
  int g = blockIdx.x, f = threadIdx.x;
  float sum = 0.f, sq = 0.f;
#pragma unroll 4
  for (int s = 0; s < 16; ++s) {
    const float* d = acc + (size_t)(s * NG + g) * 2 * NH;
    sum += d[f];
    sq += d[NH + f];
  }
  float cnt = fmaxf((float)counts[g], 1.f);
  float m = sum / cnt;
  float ex2 = sq / cnt;
  float a = ga[f];
  float var = ex2 - 2.f * a * m * m + a * a * m * m;
  float rstd = rsqrtf(var + EPSV);
  float A = gw[f] * rstd;
  Aaff[g * NH + f] = A;
  Baff[g * NH + f] = gb[f] - A * a * m;
}

// fused layer-2 finalize + classifier head + softmax
__global__ __launch_bounds__(128) void k_fin2head(const float* __restrict__ acc, const int* __restrict__ counts,
                                                  const float* __restrict__ gw, const float* __restrict__ gb,
                                                  const float* __restrict__ ga, const float* __restrict__ Wc,
                                                  const float* __restrict__ bc, float* __restrict__ outp) {
  __shared__ float pool[NH];
  __shared__ float lg[NC];
  int g = blockIdx.x, f = threadIdx.x;
  float sum = 0.f, sq = 0.f;
#pragma unroll 4
  for (int s = 0; s < 16; ++s) {
    const float* d = acc + (size_t)(s * NG + g) * 2 * NH;
    sum += d[f];
    sq += d[NH + f];
  }
  float cnt = fmaxf((float)counts[g], 1.f);
  float m = sum / cnt;
  float ex2 = sq / cnt;
  float a = ga[f];
  float var = ex2 - 2.f * a * m * m + a * a * m * m;
  float rstd = rsqrtf(var + EPSV);
  pool[f] = gw[f] * rstd * (m - a * m) + gb[f];
  __syncthreads();
  if (f < NC) {
    float s = bc[f];
    for (int h = 0; h < NH; ++h) s = fmaf(pool[h], Wc[h * NC + f], s);
    lg[f] = s;
  }
  __syncthreads();
  if (f == 0) {
    float mx = lg[0];
    for (int c = 1; c < NC; ++c) mx = fmaxf(mx, lg[c]);
    float ex[NC];
    float ssum = 0.f;
    for (int c = 0; c < NC; ++c) { ex[c] = __expf(lg[c] - mx); ssum += ex[c]; }
    float inv = 1.f / ssum;
    for (int c = 0; c < NC; ++c) outp[g * NC + c] = ex[c] * inv;
  }
}

// ---------------- launch ----------------
extern "C" void kernel_launch(void* const* d_in, const int* in_sizes, int n_in,
                              void* d_out, int out_size, void* d_ws, size_t ws_size,
                              hipStream_t stream) {
  const float* x   = (const float*)d_in[0];
  const int*   ei  = (const int*)d_in[1];
  const int*   bat = (const int*)d_in[2];
  const float* W1  = (const float*)d_in[3];
  const float* b1  = (const float*)d_in[4];
  const float* gw1 = (const float*)d_in[5];
  const float* gb1 = (const float*)d_in[6];
  const float* ga1 = (const float*)d_in[7];
  const float* W2  = (const float*)d_in[8];
  const float* b2  = (const float*)d_in[9];
  const float* gw2 = (const float*)d_in[10];
  const float* gb2 = (const float*)d_in[11];
  const float* ga2 = (const float*)d_in[12];
  const float* Wc  = (const float*)d_in[13];
  const float* bc  = (const float*)d_in[14];
  float* outp = (float*)d_out;

  char* ws = (char*)d_ws;
  size_t off = 0;
  auto alloc = [&](size_t b) { size_t p = off; off += (b + 255) & ~(size_t)255; return p; };
  int*    deg     = (int*)(ws + alloc((size_t)NN * 4));
  float*  dis     = (float*)(ws + alloc((size_t)NN * 4));
  int*    counts  = (int*)(ws + alloc(NG * 4));
  int*    gstart  = (int*)(ws + alloc((NG + 1) * 4));
  int*    offs    = (int*)(ws + alloc((size_t)NN * 4));
  int*    bsums   = (int*)(ws + alloc(512 * 4));
  int*    csr     = (int*)(ws + alloc((size_t)NE * 4));
  float*  statacc = (float*)(ws + alloc((size_t)16 * NG * 2 * NH * 4));   // 1 MB partials
  float*  Aaff    = (float*)(ws + alloc((size_t)NG * NH * 4));
  float*  Baff    = (float*)(ws + alloc((size_t)NG * NH * 4));
  ushort* WF1     = (ushort*)(ws + alloc((size_t)2048 * 8 * 2));
  ushort* WF2     = (ushort*)(ws + alloc((size_t)2048 * 8 * 2));
  uchar*  bufA    = (uchar*)(ws + alloc((size_t)(NN + 1) * NH));   // fp8 + zero row NN
  uchar*  bufB    = (uchar*)(ws + alloc((size_t)(NN + 1) * NH));   // fp8 + zero row NN
  // sort temps alias bufB (dead until first k_agg write): 6.4 (packed int) + 1.6 MB < 12.8 MB - 128B
  int* tmp   = (int*)bufB;
  int* ghist = (int*)((char*)bufB + (((size_t)NE * 4 + 255) & ~(size_t)255));
  (void)ws_size; (void)in_sizes; (void)n_in; (void)out_size;

  u64* zrowA = (u64*)(bufA + (size_t)NN * NH);
  u64* zrowB = (u64*)(bufB + (size_t)NN * NH);

  // prep: counts/gstart via binary search (batch sorted); CSR via counting sort; zero pad rows
  k_gstart2<<<1, 128, 0, stream>>>(bat, gstart, counts, zrowA, zrowB);
  k_hist<<<NBLK, 256, 0, stream>>>(ei, ghist);
  k_scan1g<<<NSB, 256, 0, stream>>>(ghist, bsums);
  k_scan2<<<1, 512, 0, stream>>>(bsums, NSB);
  k_scan3g<<<NSB, 256, 0, stream>>>(ghist, bsums);
  k_scatter<<<NBLK, 256, 0, stream>>>(ei, ghist, tmp);
  k_fine<<<NB, 256, 0, stream>>>(tmp, ghist, deg, offs, dis, csr);
  k_prepw<<<16, 256, 0, stream>>>(W1, WF1, W2, WF2);

  int gemm_grid = (NN + 63) / 64;   // 1563
  int agg_grid  = (NN + 3) / 4;     // 25000

  // layer 1
  k_gemm<false><<<gemm_grid, 256, 0, stream>>>(x, WF1, dis, bat, nullptr, nullptr, bufA);
  k_agg<<<agg_grid, 256, 0, stream>>>((const u64*)bufA, offs, deg, csr, dis, b1, (u64*)bufB);
  k_stats<<<NG * 16, 256, 0, stream>>>((const uint*)bufB, gstart, statacc);
  k_fin1<<<NG, 128, 0, stream>>>(statacc, counts, gw1, gb1, ga1, Aaff, Baff);

  // layer 2 (norm fused into GEMM A-fragment load, fp8 A-input)
  k_gemm<true><<<gemm_grid, 256, 0, stream>>>(bufB, WF2, dis, bat, Aaff, Baff, bufA);
  k_agg<<<agg_grid, 256, 0, stream>>>((const u64*)bufA, offs, deg, csr, dis, b2, (u64*)bufB);
  k_stats<<<NG * 16, 256, 0, stream>>>((const uint*)bufB, gstart, statacc);
  k_fin2head<<<NG, 128, 0, stream>>>(statacc, counts, gw2, gb2, ga2, Wc, bc, outp);
}